// Round 9
// baseline (3181.253 us; speedup 1.0000x reference)
//
#include <hip/hip_runtime.h>
#include <stdint.h>
#include <stddef.h>
#include <math.h>

#define HWSZ   3136        // 56*56
#define NPIX   100352      // 32*3136

typedef __attribute__((ext_vector_type(4))) float f32x4;
typedef __attribute__((ext_vector_type(8))) short bf16x8;
typedef __attribute__((ext_vector_type(8))) unsigned short u16x8;

__device__ __forceinline__ float bf2f(unsigned short u) {
  union { float f; unsigned int i; } v; v.i = ((unsigned int)u) << 16; return v.f;
}
__device__ __forceinline__ unsigned short f2bf(float f) {
  union { float f; unsigned int i; } v; v.f = f;
  return (unsigned short)((v.i + 0x7FFFu + ((v.i >> 16) & 1u)) >> 16);
}
__device__ __forceinline__ unsigned short sgnf_bf16(float v) {
  return (v > 0.f) ? 0x3F80u : ((v < 0.f) ? 0xBF80u : 0u);
}
__device__ __forceinline__ int isgn(float v) {
  return (v > 0.f) ? 1 : ((v < 0.f) ? -1 : 0);
}

// ---------------------------------------------------------------------------
// K0: weight prep: sign(w) as bf16, [o][c] layout
// ---------------------------------------------------------------------------
__global__ __launch_bounds__(256) void k_prepw(const float* __restrict__ w1,
    const float* __restrict__ w2, const float* __restrict__ w3,
    unsigned short* __restrict__ bs)
{
  int idx = blockIdx.x * 256 + threadIdx.x;
  int wsel = idx >> 16, rem = idx & 65535;
  const float* wp = (wsel == 0) ? w1 : ((wsel == 1) ? w2 : w3);
  float v = wp[rem];
  bs[idx] = sgnf_bf16(v);
}

// ---------------------------------------------------------------------------
// K1: depthwise 3x3 sign-conv -> c1 int8 (exact integers)
// ---------------------------------------------------------------------------
__global__ __launch_bounds__(256) void k_dwconv(const float* __restrict__ x,
    const float* __restrict__ wdw, signed char* __restrict__ c1)
{
  __shared__ signed char sp[58 * 58];
  int bid = blockIdx.x;            // n*256 + c
  int c = bid & 255;
  int t = threadIdx.x;
  const float* xp = x + (size_t)bid * HWSZ;

  for (int i = t; i < 58 * 58; i += 256) sp[i] = 0;
  __syncthreads();
  for (int px = t; px < HWSZ; px += 256) {
    float v = xp[px];
    int h = px / 56, w = px - h * 56;
    sp[(h + 1) * 58 + (w + 1)] = (signed char)isgn(v);
  }
  int ws[9];
  #pragma unroll
  for (int i = 0; i < 9; i++) ws[i] = isgn(wdw[c * 9 + i]);
  __syncthreads();

  signed char* outp = c1 + (size_t)bid * HWSZ;
  for (int px = t; px < HWSZ; px += 256) {
    int h = px / 56, w = px - h * 56;
    const signed char* r0 = sp + h * 58 + w;
    int acc = r0[0]*ws[0] + r0[1]*ws[1] + r0[2]*ws[2]
            + r0[58]*ws[3] + r0[59]*ws[4] + r0[60]*ws[5]
            + r0[116]*ws[6] + r0[117]*ws[7] + r0[118]*ws[8];
    outp[px] = (signed char)acc;
  }
}

// ---------------------------------------------------------------------------
// MEAN pass (order-free exact in f32: quarter-int partials < 2^22 units)
// ---------------------------------------------------------------------------
__global__ __launch_bounds__(256) void k_st1(const signed char* __restrict__ c1,
    const float* __restrict__ a1, float* __restrict__ P)
{
  int n = blockIdx.x >> 3, cg = blockIdx.x & 7;
  int cl = threadIdx.x & 31, s = threadIdx.x >> 5;
  int c = cg * 32 + cl;
  const signed char* pl = c1 + ((size_t)(n * 256 + c)) * HWSZ + s * 392;
  float av = a1[c];
  float sv = 0.f;
  for (int i = 0; i < 392; i++) {
    float v = (float)(int)pl[i];
    float t = (v >= 0.f) ? v : __fmul_rn(av, v);
    sv = __fadd_rn(sv, t);
  }
  __shared__ float ls[8][33];
  ls[s][cl] = sv;
  __syncthreads();
  if (s == 0) {
    float tot = 0.f;
    #pragma unroll
    for (int q = 0; q < 8; q++) tot = __fadd_rn(tot, ls[q][cl]);
    P[n * 256 + c] = tot;
  }
}

__global__ __launch_bounds__(256) void k_stT(const unsigned short* __restrict__ tb,
    float* __restrict__ P)
{
  int n = blockIdx.x >> 3, cg = blockIdx.x & 7;
  int cl = threadIdx.x & 31, s = threadIdx.x >> 5;
  int c = cg * 32 + cl;
  const unsigned short* pl = tb + ((size_t)(n * HWSZ) + s * 392) * 256 + c;
  float sv = 0.f;
  for (int i = 0; i < 392; i++)
    sv = __fadd_rn(sv, bf2f(pl[(size_t)i * 256]));
  __shared__ float ls[8][33];
  ls[s][cl] = sv;
  __syncthreads();
  if (s == 0) {
    float tot = 0.f;
    #pragma unroll
    for (int q = 0; q < 8; q++) tot = __fadd_rn(tot, ls[q][cl]);
    P[n * 256 + c] = tot;
  }
}

__global__ __launch_bounds__(256) void k_cmb(const float* __restrict__ P,
    float* __restrict__ M)
{
  int c = threadIdx.x;
  float acc = 0.f;
  for (int n = 0; n < 32; n++) acc = __fadd_rn(acc, P[n * 256 + c]);
  M[c] = __fdiv_rn(acc, 100352.0f);
}

// ===========================================================================
// VARIANCE pass — bit-exact numpy float32 pairwise order:
// pairwise(3136): perfect binary tree to 8 x 392; 392 -> (192,200) ->
// leaves (96,96,96,104); 8-accumulator leaf loop; fixed combine tree.
// ===========================================================================
#define VLEAF(EXPR)                                                          \
  float r[8];                                                                \
  {                                                                          \
    const int i0 = base;                                                     \
    _Pragma("unroll")                                                        \
    for (int j = 0; j < 8; j++) {                                            \
      int i = i0 + j; float d = __fsub_rn((EXPR), m);                        \
      r[j] = __fmul_rn(d, d);                                                \
    }                                                                        \
    for (int b = 1; b < nb; b++) {                                           \
      _Pragma("unroll")                                                      \
      for (int j = 0; j < 8; j++) {                                          \
        int i = i0 + 8 * b + j; float d = __fsub_rn((EXPR), m);              \
        r[j] = __fadd_rn(r[j], __fmul_rn(d, d));                             \
      }                                                                      \
    }                                                                        \
  }                                                                          \
  float lv = __fadd_rn(                                                      \
      __fadd_rn(__fadd_rn(r[0], r[1]), __fadd_rn(r[2], r[3])),               \
      __fadd_rn(__fadd_rn(r[4], r[5]), __fadd_rn(r[6], r[7])));

__global__ __launch_bounds__(256) void k_var1(const signed char* __restrict__ c1,
    const float* __restrict__ a1, const float* __restrict__ M,
    float* __restrict__ PV)
{
  int n = blockIdx.x, c = threadIdx.x;
  const signed char* pl = c1 + ((size_t)(n * 256 + c)) * HWSZ;
  float av = a1[c], m = M[c];
  float ls[32];
  #pragma unroll
  for (int lf = 0; lf < 32; lf++) {
    const int base = (lf >> 2) * 392 + (lf & 3) * 96;
    const int nb = ((lf & 3) == 3) ? 13 : 12;
    VLEAF(({ float v = (float)(int)pl[i];
             (v >= 0.f) ? v : __fmul_rn(av, v); }))
    ls[lf] = lv;
  }
  #pragma unroll
  for (int s = 1; s < 32; s <<= 1)
    #pragma unroll
    for (int i0 = 0; i0 < 32; i0 += 2 * s)
      ls[i0] = __fadd_rn(ls[i0], ls[i0 + s]);
  PV[n * 256 + c] = ls[0];
}

__global__ __launch_bounds__(256) void k_varT(const unsigned short* __restrict__ tb,
    const float* __restrict__ M, float* __restrict__ PV)
{
  int n = blockIdx.x, c = threadIdx.x;
  const unsigned short* pl = tb + ((size_t)(n * HWSZ)) * 256 + c;
  float m = M[c];
  float ls[32];
  #pragma unroll
  for (int lf = 0; lf < 32; lf++) {
    const int base = (lf >> 2) * 392 + (lf & 3) * 96;
    const int nb = ((lf & 3) == 3) ? 13 : 12;
    VLEAF(bf2f(pl[(size_t)i * 256]))
    ls[lf] = lv;
  }
  #pragma unroll
  for (int s = 1; s < 32; s <<= 1)
    #pragma unroll
    for (int i0 = 0; i0 < 32; i0 += 2 * s)
      ls[i0] = __fadd_rn(ls[i0], ls[i0 + s]);
  PV[n * 256 + c] = ls[0];
}

// var combine: seq over n, /100352 f32, then CORRECTLY-ROUNDED f32 rsqrt
// (computed in fp64, cast once) — covers np.power(v,-0.5)/glibc-CR family.
__global__ __launch_bounds__(256) void k_vcmb(const float* __restrict__ PV,
    float* __restrict__ R)
{
  int c = threadIdx.x;
  float acc = 0.f;
  for (int n = 0; n < 32; n++) acc = __fadd_rn(acc, PV[n * 256 + c]);
  float v = __fdiv_rn(acc, 100352.0f);
  float ve = __fadd_rn(v, 1e-5f);
  R[c] = (float)(1.0 / sqrt((double)ve));
}

// ---------------------------------------------------------------------------
// K2: apply1: SB = sign( ((t1-m)*r)*g + b + x ), f32-replica, NCHW->NHWC
// ---------------------------------------------------------------------------
__global__ __launch_bounds__(256) void k_apply1(const float* __restrict__ x,
    const signed char* __restrict__ c1, const float* __restrict__ a1,
    const float* __restrict__ M1, const float* __restrict__ R1,
    const float* __restrict__ g1, const float* __restrict__ b1,
    unsigned short* __restrict__ s1)
{
  __shared__ __align__(16) unsigned short ls[64 * 264];
  int bid = blockIdx.x;
  int n = bid / 49, pb = bid % 49;
  int px0 = pb * 64;
  int t = threadIdx.x;
  int lane = t & 63, crow = t >> 6;

  for (int j = 0; j < 64; j++) {
    int c = j * 4 + crow;
    size_t gidx = ((size_t)(n * 256 + c)) * HWSZ + px0 + lane;
    float xv = x[gidx];
    float v = (float)(int)c1[gidx];
    float av = a1[c];
    float t1 = (v >= 0.f) ? v : __fmul_rn(av, v);
    float xn = __fmul_rn(__fsub_rn(t1, M1[c]), R1[c]);
    float bn = __fadd_rn(__fmul_rn(xn, g1[c]), b1[c]);
    float o1 = __fadd_rn(bn, xv);
    ls[lane * 264 + c] = sgnf_bf16(o1);
  }
  __syncthreads();
  unsigned short* sp = s1 + ((size_t)(n * HWSZ + px0)) * 256;
  for (int j = 0; j < 8; j++) {
    int f = j * 256 + t;
    int px = f >> 5, c16 = f & 31;
    *(u16x8*)(sp + px * 256 + c16 * 8) = *(const u16x8*)(ls + px * 264 + c16 * 8);
  }
}

// ---------------------------------------------------------------------------
// K4: apply2: SB = sign( bn2(t2) + (bn1(t1)+x) ), f32-replica
// ---------------------------------------------------------------------------
__global__ __launch_bounds__(256) void k_apply2(const float* __restrict__ x,
    const signed char* __restrict__ c1, const unsigned short* __restrict__ t2,
    const float* __restrict__ a1,
    const float* __restrict__ M1, const float* __restrict__ R1,
    const float* __restrict__ g1, const float* __restrict__ b1,
    const float* __restrict__ M2, const float* __restrict__ R2,
    const float* __restrict__ g2, const float* __restrict__ b2,
    unsigned short* __restrict__ s2)
{
  __shared__ __align__(16) unsigned short lt[32 * 264];
  __shared__ __align__(16) unsigned short ls[32 * 264];
  int bid = blockIdx.x;
  int n = bid / 98, pb = bid % 98;
  int px0 = pb * 32;
  int t = threadIdx.x;

  const unsigned short* tp = t2 + ((size_t)(n * HWSZ + px0)) * 256;
  for (int j = 0; j < 4; j++) {
    int f = j * 256 + t;
    int px = f >> 5, c16 = f & 31;
    *(u16x8*)(lt + px * 264 + c16 * 8) = *(const u16x8*)(tp + px * 256 + c16 * 8);
  }
  __syncthreads();

  int lane = t & 31, crow = t >> 5;
  for (int j = 0; j < 32; j++) {
    int c = j * 8 + crow;
    size_t gidx = ((size_t)(n * 256 + c)) * HWSZ + px0 + lane;
    float xv = x[gidx];
    float v = (float)(int)c1[gidx];
    float av = a1[c];
    float t1 = (v >= 0.f) ? v : __fmul_rn(av, v);
    float xn1 = __fmul_rn(__fsub_rn(t1, M1[c]), R1[c]);
    float bn1v = __fadd_rn(__fmul_rn(xn1, g1[c]), b1[c]);
    float o1 = __fadd_rn(bn1v, xv);
    float t2v = bf2f(lt[lane * 264 + c]);
    float xn2 = __fmul_rn(__fsub_rn(t2v, M2[c]), R2[c]);
    float bn2v = __fadd_rn(__fmul_rn(xn2, g2[c]), b2[c]);
    float o2 = __fadd_rn(bn2v, o1);
    ls[lane * 264 + c] = sgnf_bf16(o2);
  }
  __syncthreads();
  unsigned short* sp = s2 + ((size_t)(n * HWSZ + px0)) * 256;
  for (int j = 0; j < 4; j++) {
    int f = j * 256 + t;
    int px = f >> 5, c16 = f & 31;
    *(u16x8*)(sp + px * 256 + c16 * 8) = *(const u16x8*)(ls + px * 264 + c16 * 8);
  }
}

// ---------------------------------------------------------------------------
// K6: apply3: SB = sign( bn3(t3) ), f32-replica, elementwise NHWC
// ---------------------------------------------------------------------------
__global__ __launch_bounds__(256) void k_apply3(const unsigned short* __restrict__ t3,
    const float* __restrict__ M3, const float* __restrict__ R3,
    const float* __restrict__ g3, const float* __restrict__ b3,
    unsigned short* __restrict__ s3)
{
  size_t idx = ((size_t)blockIdx.x * 256 + threadIdx.x) * 8;
  int c0 = (int)(idx & 255);
  u16x8 v = *(const u16x8*)(t3 + idx);
  u16x8 o;
  #pragma unroll
  for (int e = 0; e < 8; e++) {
    int c = c0 + e;
    float t = bf2f(v[e]);
    float xn = __fmul_rn(__fsub_rn(t, M3[c]), R3[c]);
    float bn = __fadd_rn(__fmul_rn(xn, g3[c]), b3[c]);
    o[e] = sgnf_bf16(bn);
  }
  *(u16x8*)(s3 + idx) = o;
}

// ---------------------------------------------------------------------------
// K8: final: out = bn4(t4) f32-replica, NHWC bf16 -> NCHW fp32
// ---------------------------------------------------------------------------
__global__ __launch_bounds__(256) void k_final(const unsigned short* __restrict__ t4,
    const float* __restrict__ M4, const float* __restrict__ R4,
    const float* __restrict__ g4, const float* __restrict__ b4,
    float* __restrict__ outp)
{
  __shared__ __align__(16) float lt[256 * 36];
  int bid = blockIdx.x;
  int n = bid / 98, pb = bid % 98;
  int px0 = pb * 32;
  int t = threadIdx.x;

  const unsigned short* tp = t4 + ((size_t)(n * HWSZ + px0)) * 256;
  for (int j = 0; j < 4; j++) {
    int f = j * 256 + t;
    int px = f >> 5, c16 = f & 31;
    u16x8 v = *(const u16x8*)(tp + px * 256 + c16 * 8);
    #pragma unroll
    for (int e = 0; e < 8; e++) {
      int c = c16 * 8 + e;
      float tv = bf2f(v[e]);
      float xn = __fmul_rn(__fsub_rn(tv, M4[c]), R4[c]);
      float bn = __fadd_rn(__fmul_rn(xn, g4[c]), b4[c]);
      lt[c * 36 + px] = bn;
    }
  }
  __syncthreads();
  for (int j = 0; j < 4; j++) {
    int f = j * 256 + t;
    int c = f >> 2, p8 = f & 3;
    f32x4 v0 = *(const f32x4*)(lt + c * 36 + p8 * 8);
    f32x4 v1 = *(const f32x4*)(lt + c * 36 + p8 * 8 + 4);
    float* op = outp + ((size_t)(n * 256 + c)) * HWSZ + px0 + p8 * 8;
    *(f32x4*)op = v0;
    *(f32x4*)(op + 4) = v1;
  }
}

// ---------------------------------------------------------------------------
// K3/5/7: GEMM: TB = prelu(SB x BS^T), exact ints via bf16 MFMA. Padded LDS.
// ---------------------------------------------------------------------------
__global__ __launch_bounds__(512) void k_gemm(
    const unsigned short* __restrict__ sIn, const unsigned short* __restrict__ bsg,
    const float* __restrict__ aP, unsigned short* __restrict__ tOut)
{
  __shared__ __align__(16) unsigned short As[128 * 72];
  __shared__ __align__(16) unsigned short Bs[256 * 72];
  const int t = threadIdx.x;
  const int lane = t & 63;
  const int wid = t >> 6;
  const int wm = wid >> 2, wn = wid & 3;
  const int lr = lane & 15, lk = lane >> 4;
  const int pix0 = blockIdx.x * 128;
  const unsigned short* Ap = sIn + (size_t)pix0 * 256;

  f32x4 acc[4][4];
  #pragma unroll
  for (int i = 0; i < 4; i++)
    #pragma unroll
    for (int j = 0; j < 4; j++)
      acc[i][j] = (f32x4){0.f, 0.f, 0.f, 0.f};

  for (int kt = 0; kt < 4; kt++) {
    const int k0 = kt * 64;
    if (kt) __syncthreads();
    #pragma unroll
    for (int j = 0; j < 2; j++) {
      int idx = j * 512 + t;
      int row = idx >> 3, kc = idx & 7;
      u16x8 v = *(const u16x8*)(Ap + (size_t)row * 256 + k0 + kc * 8);
      *(u16x8*)(As + row * 72 + kc * 8) = v;
    }
    #pragma unroll
    for (int j = 0; j < 4; j++) {
      int idx = j * 512 + t;
      int row = idx >> 3, kc = idx & 7;
      u16x8 v = *(const u16x8*)(bsg + (size_t)row * 256 + k0 + kc * 8);
      *(u16x8*)(Bs + row * 72 + kc * 8) = v;
    }
    __syncthreads();
    #pragma unroll
    for (int h = 0; h < 2; h++) {
      bf16x8 af[4], bfr[4];
      #pragma unroll
      for (int mf = 0; mf < 4; mf++)
        af[mf] = *(const bf16x8*)(As + (wm * 64 + mf * 16 + lr) * 72 + (h * 4 + lk) * 8);
      #pragma unroll
      for (int nf = 0; nf < 4; nf++)
        bfr[nf] = *(const bf16x8*)(Bs + (wn * 64 + nf * 16 + lr) * 72 + (h * 4 + lk) * 8);
      #pragma unroll
      for (int mf = 0; mf < 4; mf++)
        #pragma unroll
        for (int nf = 0; nf < 4; nf++)
          acc[mf][nf] = __builtin_amdgcn_mfma_f32_16x16x32_bf16(
              af[mf], bfr[nf], acc[mf][nf], 0, 0, 0);
    }
  }

  #pragma unroll
  for (int nf = 0; nf < 4; nf++) {
    int gcol = wn * 64 + nf * 16 + lr;
    float av = aP[gcol];
    #pragma unroll
    for (int mf = 0; mf < 4; mf++) {
      #pragma unroll
      for (int r = 0; r < 4; r++) {
        int grow = pix0 + wm * 64 + mf * 16 + lk * 4 + r;
        float u = acc[mf][nf][r];
        float tv = (u >= 0.f) ? u : __fmul_rn(av, u);   // exact quarter-ints
        tOut[(size_t)grow * 256 + gcol] = f2bf(tv);
      }
    }
  }
}

// ---------------------------------------------------------------------------
extern "C" void kernel_launch(void* const* d_in, const int* in_sizes, int n_in,
                              void* d_out, int out_size, void* d_ws, size_t ws_size,
                              hipStream_t stream)
{
  const float* x   = (const float*)d_in[0];
  const float* wdw = (const float*)d_in[1];
  const float* w1  = (const float*)d_in[2];
  const float* w2  = (const float*)d_in[3];
  const float* w3  = (const float*)d_in[4];
  const float* a1  = (const float*)d_in[5];
  const float* a2  = (const float*)d_in[6];
  const float* a3  = (const float*)d_in[7];
  const float* a4  = (const float*)d_in[8];
  const float* g1  = (const float*)d_in[9];
  const float* b1  = (const float*)d_in[10];
  const float* g2  = (const float*)d_in[11];
  const float* b2  = (const float*)d_in[12];
  const float* g3  = (const float*)d_in[13];
  const float* b3  = (const float*)d_in[14];
  const float* g4  = (const float*)d_in[15];
  const float* b4  = (const float*)d_in[16];

  char* ws = (char*)d_ws;
  unsigned short* SB = (unsigned short*)ws;                   // 51,380,224 B
  unsigned short* TB = (unsigned short*)(ws + 51380224);      // 51,380,224 B
  signed char*    c1 = (signed char*)(ws + 102760448);        // 25,690,112 B
  unsigned short* BS = (unsigned short*)(ws + 128450560);     //    393,216 B
  float*          P  = (float*)(ws + 128843776);              //     32,768 B
  float*          PV = (float*)(ws + 128876544);              //     32,768 B
  float*          MR = (float*)(ws + 128909312);              //      8,192 B
  float*          outp = (float*)d_out;                       // fp32 NCHW

  float* M1 = MR;        float* R1 = MR + 256;
  float* M2 = MR + 512;  float* R2 = MR + 768;
  float* M3 = MR + 1024; float* R3 = MR + 1280;
  float* M4 = MR + 1536; float* R4 = MR + 1792;

  k_prepw <<<dim3(768),  dim3(256), 0, stream>>>(w1, w2, w3, BS);
  k_dwconv<<<dim3(8192), dim3(256), 0, stream>>>(x, wdw, c1);

  // BN1 stats on prelu(c1): exact mean, np-ordered var, CR rsqrt
  k_st1   <<<dim3(256),  dim3(256), 0, stream>>>(c1, a1, P);
  k_cmb   <<<dim3(1),    dim3(256), 0, stream>>>(P, M1);
  k_var1  <<<dim3(32),   dim3(256), 0, stream>>>(c1, a1, M1, PV);
  k_vcmb  <<<dim3(1),    dim3(256), 0, stream>>>(PV, R1);
  k_apply1<<<dim3(1568), dim3(256), 0, stream>>>(x, c1, a1, M1, R1, g1, b1, SB);

  // layer 2
  k_gemm  <<<dim3(784),  dim3(512), 0, stream>>>(SB, BS, a2, TB);
  k_stT   <<<dim3(256),  dim3(256), 0, stream>>>(TB, P);
  k_cmb   <<<dim3(1),    dim3(256), 0, stream>>>(P, M2);
  k_varT  <<<dim3(32),   dim3(256), 0, stream>>>(TB, M2, PV);
  k_vcmb  <<<dim3(1),    dim3(256), 0, stream>>>(PV, R2);
  k_apply2<<<dim3(3136), dim3(256), 0, stream>>>(x, c1, TB, a1,
                                                 M1, R1, g1, b1, M2, R2, g2, b2, SB);

  // layer 3
  k_gemm  <<<dim3(784),  dim3(512), 0, stream>>>(SB, BS + 65536, a3, TB);
  k_stT   <<<dim3(256),  dim3(256), 0, stream>>>(TB, P);
  k_cmb   <<<dim3(1),    dim3(256), 0, stream>>>(P, M3);
  k_varT  <<<dim3(32),   dim3(256), 0, stream>>>(TB, M3, PV);
  k_vcmb  <<<dim3(1),    dim3(256), 0, stream>>>(PV, R3);
  k_apply3<<<dim3(12544),dim3(256), 0, stream>>>(TB, M3, R3, g3, b3, SB);

  // layer 4
  k_gemm  <<<dim3(784),  dim3(512), 0, stream>>>(SB, BS + 131072, a4, TB);
  k_stT   <<<dim3(256),  dim3(256), 0, stream>>>(TB, P);
  k_cmb   <<<dim3(1),    dim3(256), 0, stream>>>(P, M4);
  k_varT  <<<dim3(32),   dim3(256), 0, stream>>>(TB, M4, PV);
  k_vcmb  <<<dim3(1),    dim3(256), 0, stream>>>(PV, R4);
  k_final <<<dim3(3136), dim3(256), 0, stream>>>(TB, M4, R4, g4, b4, outp);
}

// Round 10
// 755.033 us; speedup vs baseline: 4.2134x; 4.2134x over previous
//
#include <hip/hip_runtime.h>
#include <stdint.h>
#include <stddef.h>
#include <math.h>

#define HWSZ   3136        // 56*56
#define NPIX   100352      // 32*3136

typedef __attribute__((ext_vector_type(4))) float f32x4;
typedef __attribute__((ext_vector_type(8))) short bf16x8;
typedef __attribute__((ext_vector_type(8))) unsigned short u16x8;

__device__ __forceinline__ float bf2f(unsigned short u) {
  union { float f; unsigned int i; } v; v.i = ((unsigned int)u) << 16; return v.f;
}
__device__ __forceinline__ unsigned short f2bf(float f) {
  union { float f; unsigned int i; } v; v.f = f;
  return (unsigned short)((v.i + 0x7FFFu + ((v.i >> 16) & 1u)) >> 16);
}
__device__ __forceinline__ unsigned short sgnf_bf16(float v) {
  return (v > 0.f) ? 0x3F80u : ((v < 0.f) ? 0xBF80u : 0u);
}
__device__ __forceinline__ int isgn(float v) {
  return (v > 0.f) ? 1 : ((v < 0.f) ? -1 : 0);
}

// ---------------------------------------------------------------------------
// K0: weight prep: sign(w) as bf16, [o][c] layout
// ---------------------------------------------------------------------------
__global__ __launch_bounds__(256) void k_prepw(const float* __restrict__ w1,
    const float* __restrict__ w2, const float* __restrict__ w3,
    unsigned short* __restrict__ bs)
{
  int idx = blockIdx.x * 256 + threadIdx.x;
  int wsel = idx >> 16, rem = idx & 65535;
  const float* wp = (wsel == 0) ? w1 : ((wsel == 1) ? w2 : w3);
  float v = wp[rem];
  bs[idx] = sgnf_bf16(v);
}

// ---------------------------------------------------------------------------
// K1: depthwise 3x3 sign-conv -> c1 int8 + fused plane mean-partials
// (plane sums of prelu values are exact quarter-int f32 sums -> order-free)
// ---------------------------------------------------------------------------
__global__ __launch_bounds__(256) void k_dwconv(const float* __restrict__ x,
    const float* __restrict__ wdw, const float* __restrict__ a1,
    signed char* __restrict__ c1, float* __restrict__ P1)
{
  __shared__ signed char sp[58 * 58];
  __shared__ float rs[4];
  int bid = blockIdx.x;            // n*256 + c
  int c = bid & 255;
  int t = threadIdx.x;
  const float* xp = x + (size_t)bid * HWSZ;

  for (int i = t; i < 58 * 58; i += 256) sp[i] = 0;
  __syncthreads();
  for (int px = t; px < HWSZ; px += 256) {
    float v = xp[px];
    int h = px / 56, w = px - h * 56;
    sp[(h + 1) * 58 + (w + 1)] = (signed char)isgn(v);
  }
  int ws[9];
  #pragma unroll
  for (int i = 0; i < 9; i++) ws[i] = isgn(wdw[c * 9 + i]);
  float av = a1[c];
  __syncthreads();

  float lsum = 0.f;
  signed char* outp = c1 + (size_t)bid * HWSZ;
  for (int px = t; px < HWSZ; px += 256) {
    int h = px / 56, w = px - h * 56;
    const signed char* r0 = sp + h * 58 + w;
    int acc = r0[0]*ws[0] + r0[1]*ws[1] + r0[2]*ws[2]
            + r0[58]*ws[3] + r0[59]*ws[4] + r0[60]*ws[5]
            + r0[116]*ws[6] + r0[117]*ws[7] + r0[118]*ws[8];
    outp[px] = (signed char)acc;
    float u = (float)acc;
    lsum += (u >= 0.f) ? u : av * u;     // exact quarter-ints
  }
  for (int o = 32; o > 0; o >>= 1) lsum += __shfl_xor(lsum, o);
  if ((t & 63) == 0) rs[t >> 6] = lsum;
  __syncthreads();
  if (t == 0) P1[bid] = ((rs[0] + rs[1]) + (rs[2] + rs[3]));
}

// mean combine (layer1): seq over 32 plane sums (exact), /100352 f32
__global__ __launch_bounds__(256) void k_cmb(const float* __restrict__ P,
    float* __restrict__ M)
{
  int c = threadIdx.x;
  float acc = 0.f;
  for (int n = 0; n < 32; n++) acc = __fadd_rn(acc, P[n * 256 + c]);
  M[c] = __fdiv_rn(acc, 100352.0f);
}

// mean combine (gemm layers): seq over 784 block partials (exact)
__global__ __launch_bounds__(256) void k_cmbG(const float* __restrict__ PM,
    float* __restrict__ M)
{
  int c = threadIdx.x;
  float acc = 0.f;
  for (int b = 0; b < 784; b++) acc = __fadd_rn(acc, PM[(size_t)b * 256 + c]);
  M[c] = __fdiv_rn(acc, 100352.0f);
}

// ===========================================================================
// VARIANCE — bit-exact numpy float32 pairwise order, parallelized.
// Tree per plane (3136): 8 chunks of 392; 392 = (l0+l1)+(l2+l3),
// leaves (96,96,96,104) at offsets (0,96,192,288); leaf = 8-acc loop;
// chunks combine ((c0+c1)+(c2+c3))+((c4+c5)+(c6+c7)); seq over n; CR rsqrt.
// ===========================================================================

// var1: one block per (n,c) plane (NCHW int8); 256 thr = 32 leaves x 8 accs
__global__ __launch_bounds__(256) void k_var1(const signed char* __restrict__ c1,
    const float* __restrict__ a1, const float* __restrict__ M,
    float* __restrict__ PV)
{
  __shared__ float rr[256];
  __shared__ float lsm[32];
  int bid = blockIdx.x;
  int c = bid & 255;
  int t = threadIdx.x;
  int lf = t >> 3, j = t & 7;
  const int base = (lf >> 2) * 392 + (lf & 3) * 96;
  const int nb = ((lf & 3) == 3) ? 13 : 12;
  const signed char* pl = c1 + (size_t)bid * HWSZ + base + j;
  float av = a1[c], m = M[c];
  float r;
  {
    float v = (float)(int)pl[0];
    float tt = (v >= 0.f) ? v : __fmul_rn(av, v);
    float d = __fsub_rn(tt, m);
    r = __fmul_rn(d, d);
  }
  for (int b = 1; b < nb; b++) {
    float v = (float)(int)pl[8 * b];
    float tt = (v >= 0.f) ? v : __fmul_rn(av, v);
    float d = __fsub_rn(tt, m);
    r = __fadd_rn(r, __fmul_rn(d, d));
  }
  rr[t] = r;
  __syncthreads();
  if (j == 0) {
    const float* q = rr + lf * 8;
    lsm[lf] = __fadd_rn(
        __fadd_rn(__fadd_rn(q[0], q[1]), __fadd_rn(q[2], q[3])),
        __fadd_rn(__fadd_rn(q[4], q[5]), __fadd_rn(q[6], q[7])));
  }
  __syncthreads();
  if (t == 0) {
    float ch[8];
    #pragma unroll
    for (int q8 = 0; q8 < 8; q8++)
      ch[q8] = __fadd_rn(__fadd_rn(lsm[q8 * 4], lsm[q8 * 4 + 1]),
                         __fadd_rn(lsm[q8 * 4 + 2], lsm[q8 * 4 + 3]));
    float s0 = __fadd_rn(ch[0], ch[1]), s1 = __fadd_rn(ch[2], ch[3]);
    float s2 = __fadd_rn(ch[4], ch[5]), s3 = __fadd_rn(ch[6], ch[7]);
    PV[bid] = __fadd_rn(__fadd_rn(s0, s1), __fadd_rn(s2, s3));
  }
}

// var combine (layer1): seq over n plane sums, /100352, CR f32 rsqrt
__global__ __launch_bounds__(256) void k_vcmb(const float* __restrict__ PV,
    float* __restrict__ R)
{
  int c = threadIdx.x;
  float acc = 0.f;
  for (int n = 0; n < 32; n++) acc = __fadd_rn(acc, PV[n * 256 + c]);
  float v = __fdiv_rn(acc, 100352.0f);
  R[c] = (float)(1.0 / sqrt((double)__fadd_rn(v, 1e-5f)));
}

// varT: one block per (n, leaf) (NHWC bf16); 256 thr = 256 channels
__global__ __launch_bounds__(256) void k_varT(const unsigned short* __restrict__ tb,
    const float* __restrict__ M, float* __restrict__ PVL)
{
  int n = blockIdx.x >> 5, lf = blockIdx.x & 31;
  int c = threadIdx.x;
  const int base = (lf >> 2) * 392 + (lf & 3) * 96;
  const int nb = ((lf & 3) == 3) ? 13 : 12;
  const unsigned short* pl = tb + ((size_t)n * HWSZ + base) * 256 + c;
  float m = M[c];
  float r[8];
  #pragma unroll
  for (int j = 0; j < 8; j++) {
    float d = __fsub_rn(bf2f(pl[(size_t)j * 256]), m);
    r[j] = __fmul_rn(d, d);
  }
  for (int b = 1; b < nb; b++) {
    #pragma unroll
    for (int j = 0; j < 8; j++) {
      float d = __fsub_rn(bf2f(pl[(size_t)(8 * b + j) * 256]), m);
      r[j] = __fadd_rn(r[j], __fmul_rn(d, d));
    }
  }
  float lv = __fadd_rn(
      __fadd_rn(__fadd_rn(r[0], r[1]), __fadd_rn(r[2], r[3])),
      __fadd_rn(__fadd_rn(r[4], r[5]), __fadd_rn(r[6], r[7])));
  PVL[(size_t)blockIdx.x * 256 + c] = lv;
}

// varT combine: exact tree over 32 leaves, seq over n, /100352, CR rsqrt
__global__ __launch_bounds__(256) void k_vcmbT(const float* __restrict__ PVL,
    float* __restrict__ R)
{
  int c = threadIdx.x;
  float acc = 0.f;
  for (int n = 0; n < 32; n++) {
    float ch[8];
    #pragma unroll
    for (int q = 0; q < 8; q++) {
      const float* p = PVL + ((size_t)(n * 32 + q * 4)) * 256 + c;
      ch[q] = __fadd_rn(__fadd_rn(p[0], p[256]), __fadd_rn(p[512], p[768]));
    }
    float s0 = __fadd_rn(ch[0], ch[1]), s1 = __fadd_rn(ch[2], ch[3]);
    float s2 = __fadd_rn(ch[4], ch[5]), s3 = __fadd_rn(ch[6], ch[7]);
    float plane = __fadd_rn(__fadd_rn(s0, s1), __fadd_rn(s2, s3));
    acc = __fadd_rn(acc, plane);
  }
  float v = __fdiv_rn(acc, 100352.0f);
  R[c] = (float)(1.0 / sqrt((double)__fadd_rn(v, 1e-5f)));
}

// ---------------------------------------------------------------------------
// K2: apply1: SB = sign( ((t1-m)*r)*g + b + x ), f32-replica, NCHW->NHWC
// ---------------------------------------------------------------------------
__global__ __launch_bounds__(256) void k_apply1(const float* __restrict__ x,
    const signed char* __restrict__ c1, const float* __restrict__ a1,
    const float* __restrict__ M1, const float* __restrict__ R1,
    const float* __restrict__ g1, const float* __restrict__ b1,
    unsigned short* __restrict__ s1)
{
  __shared__ __align__(16) unsigned short ls[64 * 264];
  int bid = blockIdx.x;
  int n = bid / 49, pb = bid % 49;
  int px0 = pb * 64;
  int t = threadIdx.x;
  int lane = t & 63, crow = t >> 6;

  for (int j = 0; j < 64; j++) {
    int c = j * 4 + crow;
    size_t gidx = ((size_t)(n * 256 + c)) * HWSZ + px0 + lane;
    float xv = x[gidx];
    float v = (float)(int)c1[gidx];
    float av = a1[c];
    float t1 = (v >= 0.f) ? v : __fmul_rn(av, v);
    float xn = __fmul_rn(__fsub_rn(t1, M1[c]), R1[c]);
    float bn = __fadd_rn(__fmul_rn(xn, g1[c]), b1[c]);
    float o1 = __fadd_rn(bn, xv);
    ls[lane * 264 + c] = sgnf_bf16(o1);
  }
  __syncthreads();
  unsigned short* sp = s1 + ((size_t)(n * HWSZ + px0)) * 256;
  for (int j = 0; j < 8; j++) {
    int f = j * 256 + t;
    int px = f >> 5, c16 = f & 31;
    *(u16x8*)(sp + px * 256 + c16 * 8) = *(const u16x8*)(ls + px * 264 + c16 * 8);
  }
}

// ---------------------------------------------------------------------------
// K4: apply2: SB = sign( bn2(t2) + (bn1(t1)+x) ), f32-replica
// ---------------------------------------------------------------------------
__global__ __launch_bounds__(256) void k_apply2(const float* __restrict__ x,
    const signed char* __restrict__ c1, const unsigned short* __restrict__ t2,
    const float* __restrict__ a1,
    const float* __restrict__ M1, const float* __restrict__ R1,
    const float* __restrict__ g1, const float* __restrict__ b1,
    const float* __restrict__ M2, const float* __restrict__ R2,
    const float* __restrict__ g2, const float* __restrict__ b2,
    unsigned short* __restrict__ s2)
{
  __shared__ __align__(16) unsigned short lt[32 * 264];
  __shared__ __align__(16) unsigned short ls[32 * 264];
  int bid = blockIdx.x;
  int n = bid / 98, pb = bid % 98;
  int px0 = pb * 32;
  int t = threadIdx.x;

  const unsigned short* tp = t2 + ((size_t)(n * HWSZ + px0)) * 256;
  for (int j = 0; j < 4; j++) {
    int f = j * 256 + t;
    int px = f >> 5, c16 = f & 31;
    *(u16x8*)(lt + px * 264 + c16 * 8) = *(const u16x8*)(tp + px * 256 + c16 * 8);
  }
  __syncthreads();

  int lane = t & 31, crow = t >> 5;
  for (int j = 0; j < 32; j++) {
    int c = j * 8 + crow;
    size_t gidx = ((size_t)(n * 256 + c)) * HWSZ + px0 + lane;
    float xv = x[gidx];
    float v = (float)(int)c1[gidx];
    float av = a1[c];
    float t1 = (v >= 0.f) ? v : __fmul_rn(av, v);
    float xn1 = __fmul_rn(__fsub_rn(t1, M1[c]), R1[c]);
    float bn1v = __fadd_rn(__fmul_rn(xn1, g1[c]), b1[c]);
    float o1 = __fadd_rn(bn1v, xv);
    float t2v = bf2f(lt[lane * 264 + c]);
    float xn2 = __fmul_rn(__fsub_rn(t2v, M2[c]), R2[c]);
    float bn2v = __fadd_rn(__fmul_rn(xn2, g2[c]), b2[c]);
    float o2 = __fadd_rn(bn2v, o1);
    ls[lane * 264 + c] = sgnf_bf16(o2);
  }
  __syncthreads();
  unsigned short* sp = s2 + ((size_t)(n * HWSZ + px0)) * 256;
  for (int j = 0; j < 4; j++) {
    int f = j * 256 + t;
    int px = f >> 5, c16 = f & 31;
    *(u16x8*)(sp + px * 256 + c16 * 8) = *(const u16x8*)(ls + px * 264 + c16 * 8);
  }
}

// ---------------------------------------------------------------------------
// K6: apply3: SB = sign( bn3(t3) ), f32-replica, elementwise NHWC
// ---------------------------------------------------------------------------
__global__ __launch_bounds__(256) void k_apply3(const unsigned short* __restrict__ t3,
    const float* __restrict__ M3, const float* __restrict__ R3,
    const float* __restrict__ g3, const float* __restrict__ b3,
    unsigned short* __restrict__ s3)
{
  size_t idx = ((size_t)blockIdx.x * 256 + threadIdx.x) * 8;
  int c0 = (int)(idx & 255);
  u16x8 v = *(const u16x8*)(t3 + idx);
  u16x8 o;
  #pragma unroll
  for (int e = 0; e < 8; e++) {
    int c = c0 + e;
    float t = bf2f(v[e]);
    float xn = __fmul_rn(__fsub_rn(t, M3[c]), R3[c]);
    float bn = __fadd_rn(__fmul_rn(xn, g3[c]), b3[c]);
    o[e] = sgnf_bf16(bn);
  }
  *(u16x8*)(s3 + idx) = o;
}

// ---------------------------------------------------------------------------
// K8: final: out = bn4(t4) f32-replica, NHWC bf16 -> NCHW fp32
// ---------------------------------------------------------------------------
__global__ __launch_bounds__(256) void k_final(const unsigned short* __restrict__ t4,
    const float* __restrict__ M4, const float* __restrict__ R4,
    const float* __restrict__ g4, const float* __restrict__ b4,
    float* __restrict__ outp)
{
  __shared__ __align__(16) float lt[256 * 36];
  int bid = blockIdx.x;
  int n = bid / 98, pb = bid % 98;
  int px0 = pb * 32;
  int t = threadIdx.x;

  const unsigned short* tp = t4 + ((size_t)(n * HWSZ + px0)) * 256;
  for (int j = 0; j < 4; j++) {
    int f = j * 256 + t;
    int px = f >> 5, c16 = f & 31;
    u16x8 v = *(const u16x8*)(tp + px * 256 + c16 * 8);
    #pragma unroll
    for (int e = 0; e < 8; e++) {
      int c = c16 * 8 + e;
      float tv = bf2f(v[e]);
      float xn = __fmul_rn(__fsub_rn(tv, M4[c]), R4[c]);
      float bn = __fadd_rn(__fmul_rn(xn, g4[c]), b4[c]);
      lt[c * 36 + px] = bn;
    }
  }
  __syncthreads();
  for (int j = 0; j < 4; j++) {
    int f = j * 256 + t;
    int c = f >> 2, p8 = f & 3;
    f32x4 v0 = *(const f32x4*)(lt + c * 36 + p8 * 8);
    f32x4 v1 = *(const f32x4*)(lt + c * 36 + p8 * 8 + 4);
    float* op = outp + ((size_t)(n * 256 + c)) * HWSZ + px0 + p8 * 8;
    *(f32x4*)op = v0;
    *(f32x4*)(op + 4) = v1;
  }
}

// ---------------------------------------------------------------------------
// K3/5/7: GEMM: TB = prelu(SB x BS^T), exact ints via bf16 MFMA, padded LDS,
// + fused per-block column mean-partials (exact int f32 sums, order-free)
// ---------------------------------------------------------------------------
__global__ __launch_bounds__(512) void k_gemm(
    const unsigned short* __restrict__ sIn, const unsigned short* __restrict__ bsg,
    const float* __restrict__ aP, unsigned short* __restrict__ tOut,
    float* __restrict__ PM)
{
  __shared__ __align__(16) unsigned short As[128 * 72];
  __shared__ __align__(16) unsigned short Bs[256 * 72];
  __shared__ float red[8][4][16];
  const int t = threadIdx.x;
  const int lane = t & 63;
  const int wid = t >> 6;
  const int wm = wid >> 2, wn = wid & 3;
  const int lr = lane & 15, lk = lane >> 4;
  const int pix0 = blockIdx.x * 128;
  const unsigned short* Ap = sIn + (size_t)pix0 * 256;

  f32x4 acc[4][4];
  #pragma unroll
  for (int i = 0; i < 4; i++)
    #pragma unroll
    for (int j = 0; j < 4; j++)
      acc[i][j] = (f32x4){0.f, 0.f, 0.f, 0.f};

  for (int kt = 0; kt < 4; kt++) {
    const int k0 = kt * 64;
    if (kt) __syncthreads();
    #pragma unroll
    for (int j = 0; j < 2; j++) {
      int idx = j * 512 + t;
      int row = idx >> 3, kc = idx & 7;
      u16x8 v = *(const u16x8*)(Ap + (size_t)row * 256 + k0 + kc * 8);
      *(u16x8*)(As + row * 72 + kc * 8) = v;
    }
    #pragma unroll
    for (int j = 0; j < 4; j++) {
      int idx = j * 512 + t;
      int row = idx >> 3, kc = idx & 7;
      u16x8 v = *(const u16x8*)(bsg + (size_t)row * 256 + k0 + kc * 8);
      *(u16x8*)(Bs + row * 72 + kc * 8) = v;
    }
    __syncthreads();
    #pragma unroll
    for (int h = 0; h < 2; h++) {
      bf16x8 af[4], bfr[4];
      #pragma unroll
      for (int mf = 0; mf < 4; mf++)
        af[mf] = *(const bf16x8*)(As + (wm * 64 + mf * 16 + lr) * 72 + (h * 4 + lk) * 8);
      #pragma unroll
      for (int nf = 0; nf < 4; nf++)
        bfr[nf] = *(const bf16x8*)(Bs + (wn * 64 + nf * 16 + lr) * 72 + (h * 4 + lk) * 8);
      #pragma unroll
      for (int mf = 0; mf < 4; mf++)
        #pragma unroll
        for (int nf = 0; nf < 4; nf++)
          acc[mf][nf] = __builtin_amdgcn_mfma_f32_16x16x32_bf16(
              af[mf], bfr[nf], acc[mf][nf], 0, 0, 0);
    }
  }

  float csum[4];
  #pragma unroll
  for (int nf = 0; nf < 4; nf++) csum[nf] = 0.f;

  #pragma unroll
  for (int nf = 0; nf < 4; nf++) {
    int gcol = wn * 64 + nf * 16 + lr;
    float av = aP[gcol];
    #pragma unroll
    for (int mf = 0; mf < 4; mf++) {
      #pragma unroll
      for (int r = 0; r < 4; r++) {
        int grow = pix0 + wm * 64 + mf * 16 + lk * 4 + r;
        float u = acc[mf][nf][r];
        float tv = (u >= 0.f) ? u : __fmul_rn(av, u);   // exact quarter-ints
        tOut[(size_t)grow * 256 + gcol] = f2bf(tv);
        csum[nf] = __fadd_rn(csum[nf], tv);             // exact, order-free
      }
    }
  }
  // reduce over lk within wave (lanes xor 16, 32), exact
  #pragma unroll
  for (int nf = 0; nf < 4; nf++) {
    csum[nf] = __fadd_rn(csum[nf], __shfl_xor(csum[nf], 16));
    csum[nf] = __fadd_rn(csum[nf], __shfl_xor(csum[nf], 32));
  }
  if (lane < 16) {
    #pragma unroll
    for (int nf = 0; nf < 4; nf++) red[wid][nf][lane] = csum[nf];
  }
  __syncthreads();
  if (t < 256) {
    int wn2 = t >> 6, nf2 = (t >> 4) & 3, lr2 = t & 15;
    PM[(size_t)blockIdx.x * 256 + t] =
        __fadd_rn(red[wn2][nf2][lr2], red[wn2 + 4][nf2][lr2]);
  }
}

// ---------------------------------------------------------------------------
extern "C" void kernel_launch(void* const* d_in, const int* in_sizes, int n_in,
                              void* d_out, int out_size, void* d_ws, size_t ws_size,
                              hipStream_t stream)
{
  const float* x   = (const float*)d_in[0];
  const float* wdw = (const float*)d_in[1];
  const float* w1  = (const float*)d_in[2];
  const float* w2  = (const float*)d_in[3];
  const float* w3  = (const float*)d_in[4];
  const float* a1  = (const float*)d_in[5];
  const float* a2  = (const float*)d_in[6];
  const float* a3  = (const float*)d_in[7];
  const float* a4  = (const float*)d_in[8];
  const float* g1  = (const float*)d_in[9];
  const float* b1  = (const float*)d_in[10];
  const float* g2  = (const float*)d_in[11];
  const float* b2  = (const float*)d_in[12];
  const float* g3  = (const float*)d_in[13];
  const float* b3  = (const float*)d_in[14];
  const float* g4  = (const float*)d_in[15];
  const float* b4  = (const float*)d_in[16];

  char* ws = (char*)d_ws;
  unsigned short* SB  = (unsigned short*)ws;                  // 51,380,224 B
  unsigned short* TB  = (unsigned short*)(ws + 51380224);     // 51,380,224 B
  signed char*    c1  = (signed char*)(ws + 102760448);       // 25,690,112 B
  unsigned short* BS  = (unsigned short*)(ws + 128450560);    //    393,216 B
  float*          BIG = (float*)(ws + 128843776);             //  1,048,576 B (PM / P1 / PVL, time-shared)
  float*          PV  = (float*)(ws + 129892352);             //     32,768 B
  float*          MR  = (float*)(ws + 129925120);             //      8,192 B
  float*          outp = (float*)d_out;                       // fp32 NCHW

  float* P1  = BIG;   // [32][256] plane sums (layer1)
  float* PM  = BIG;   // [784][256] gemm block sums
  float* PVL = BIG;   // [1024][256] varT leaf sums
  float* M1 = MR;        float* R1 = MR + 256;
  float* M2 = MR + 512;  float* R2 = MR + 768;
  float* M3 = MR + 1024; float* R3 = MR + 1280;
  float* M4 = MR + 1536; float* R4 = MR + 1792;

  k_prepw <<<dim3(768),  dim3(256), 0, stream>>>(w1, w2, w3, BS);
  k_dwconv<<<dim3(8192), dim3(256), 0, stream>>>(x, wdw, a1, c1, P1);

  // BN1: fused mean partials, parallel np-ordered var, CR rsqrt
  k_cmb   <<<dim3(1),    dim3(256), 0, stream>>>(P1, M1);
  k_var1  <<<dim3(8192), dim3(256), 0, stream>>>(c1, a1, M1, PV);
  k_vcmb  <<<dim3(1),    dim3(256), 0, stream>>>(PV, R1);
  k_apply1<<<dim3(1568), dim3(256), 0, stream>>>(x, c1, a1, M1, R1, g1, b1, SB);

  // layer 2
  k_gemm  <<<dim3(784),  dim3(512), 0, stream>>>(SB, BS, a2, TB, PM);
  k_cmbG  <<<dim3(1),    dim3(256), 0, stream>>>(PM, M2);
  k_varT  <<<dim3(1024), dim3(256), 0, stream>>>(TB, M2, PVL);
  k_vcmbT <<<dim3(1),    dim3(256), 0, stream>>>(PVL, R2);
  k_apply2<<<dim3(3136), dim3(256), 0, stream>>>(x, c1, TB, a1,
                                                 M1, R1, g1, b1, M2, R2, g2, b2, SB);

  // layer 3
  k_gemm  <<<dim3(784),  dim3(512), 0, stream>>>(SB, BS + 65536, a3, TB, PM);
  k_cmbG  <<<dim3(1),    dim3(256), 0, stream>>>(PM, M3);
  k_varT  <<<dim3(1024), dim3(256), 0, stream>>>(TB, M3, PVL);
  k_vcmbT <<<dim3(1),    dim3(256), 0, stream>>>(PVL, R3);
  k_apply3<<<dim3(12544),dim3(256), 0, stream>>>(TB, M3, R3, g3, b3, SB);

  // layer 4
  k_gemm  <<<dim3(784),  dim3(512), 0, stream>>>(SB, BS + 131072, a4, TB, PM);
  k_cmbG  <<<dim3(1),    dim3(256), 0, stream>>>(PM, M4);
  k_varT  <<<dim3(1024), dim3(256), 0, stream>>>(TB, M4, PVL);
  k_vcmbT <<<dim3(1),    dim3(256), 0, stream>>>(PVL, R4);
  k_final <<<dim3(3136), dim3(256), 0, stream>>>(TB, M4, R4, g4, b4, outp);
}

// Round 11
// 673.045 us; speedup vs baseline: 4.7267x; 1.1218x over previous
//
#include <hip/hip_runtime.h>
#include <stdint.h>
#include <stddef.h>
#include <math.h>

#define HWSZ   3136        // 56*56
#define NPIX   100352      // 32*3136

typedef __attribute__((ext_vector_type(4))) float f32x4;
typedef __attribute__((ext_vector_type(8))) short bf16x8;
typedef __attribute__((ext_vector_type(8))) unsigned short u16x8;

__device__ __forceinline__ float bf2f(unsigned short u) {
  union { float f; unsigned int i; } v; v.i = ((unsigned int)u) << 16; return v.f;
}
__device__ __forceinline__ unsigned short f2bf(float f) {
  union { float f; unsigned int i; } v; v.f = f;
  return (unsigned short)((v.i + 0x7FFFu + ((v.i >> 16) & 1u)) >> 16);
}
__device__ __forceinline__ unsigned short sgnf_bf16(float v) {
  return (v > 0.f) ? 0x3F80u : ((v < 0.f) ? 0xBF80u : 0u);
}
__device__ __forceinline__ int isgn(float v) {
  return (v > 0.f) ? 1 : ((v < 0.f) ? -1 : 0);
}

// ---------------------------------------------------------------------------
// K0: weight prep: sign(w) as bf16, [o][c] layout
// ---------------------------------------------------------------------------
__global__ __launch_bounds__(256) void k_prepw(const float* __restrict__ w1,
    const float* __restrict__ w2, const float* __restrict__ w3,
    unsigned short* __restrict__ bs)
{
  int idx = blockIdx.x * 256 + threadIdx.x;
  int wsel = idx >> 16, rem = idx & 65535;
  const float* wp = (wsel == 0) ? w1 : ((wsel == 1) ? w2 : w3);
  float v = wp[rem];
  bs[idx] = sgnf_bf16(v);
}

// ---------------------------------------------------------------------------
// K1: depthwise 3x3 sign-conv -> c1 int8 + fused plane mean-partials.
// Vectorized: f32x4 x-loads; LDS float sign-plane (stride 60, 2-col ghost);
// 4 outputs/thread via 6 ds_read_b128; packed uint c1 stores.
// All arithmetic integer-exact in f32.
// ---------------------------------------------------------------------------
__global__ __launch_bounds__(256) void k_dwconv(const float* __restrict__ x,
    const float* __restrict__ wdw, const float* __restrict__ a1,
    signed char* __restrict__ c1, float* __restrict__ P1)
{
  __shared__ float sp[58 * 60];    // row r = h+1 (h=-1..56), col = w+2 (w=-2..57)
  __shared__ float rs[4];
  int bid = blockIdx.x;            // n*256 + c
  int c = bid & 255;
  int t = threadIdx.x;
  const float* xp = x + (size_t)bid * HWSZ;

  for (int i = t; i < 58 * 60; i += 256) sp[i] = 0.f;
  __syncthreads();
  for (int q = t; q < 784; q += 256) {
    int h = q / 14, w0 = (q - h * 14) * 4;
    f32x4 v = *(const f32x4*)(xp + h * 56 + w0);
    float* d = sp + (h + 1) * 60 + (w0 + 2);
    d[0] = (float)isgn(v[0]);
    d[1] = (float)isgn(v[1]);
    d[2] = (float)isgn(v[2]);
    d[3] = (float)isgn(v[3]);
  }
  float wsf[9];
  #pragma unroll
  for (int i = 0; i < 9; i++) wsf[i] = (float)isgn(wdw[c * 9 + i]);
  float av = a1[c];
  __syncthreads();

  float lsum = 0.f;
  signed char* outp = c1 + (size_t)bid * HWSZ;
  for (int q = t; q < 784; q += 256) {
    int h = q / 14, w0 = (q - h * 14) * 4;
    float win[3][8];
    #pragma unroll
    for (int r = 0; r < 3; r++) {
      const float* rowp = sp + (h + r) * 60 + w0;   // col base = w0 -> w = w0-2
      *(f32x4*)(&win[r][0]) = *(const f32x4*)rowp;
      *(f32x4*)(&win[r][4]) = *(const f32x4*)(rowp + 4);
    }
    unsigned int pk = 0;
    #pragma unroll
    for (int j = 0; j < 4; j++) {
      float acc = 0.f;
      #pragma unroll
      for (int r = 0; r < 3; r++) {
        acc = fmaf(win[r][j + 1], wsf[r * 3 + 0], acc);
        acc = fmaf(win[r][j + 2], wsf[r * 3 + 1], acc);
        acc = fmaf(win[r][j + 3], wsf[r * 3 + 2], acc);
      }
      int ia = (int)acc;
      pk |= ((unsigned int)(unsigned char)(signed char)ia) << (8 * j);
      lsum += (acc >= 0.f) ? acc : av * acc;       // exact quarter-ints
    }
    *(unsigned int*)(void*)(outp + h * 56 + w0) = pk;
  }
  for (int o = 32; o > 0; o >>= 1) lsum += __shfl_xor(lsum, o);
  if ((t & 63) == 0) rs[t >> 6] = lsum;
  __syncthreads();
  if (t == 0) P1[bid] = ((rs[0] + rs[1]) + (rs[2] + rs[3]));
}

// mean combine (layer1): seq over 32 plane sums (exact), /100352 f32
__global__ __launch_bounds__(256) void k_cmb(const float* __restrict__ P,
    float* __restrict__ M)
{
  int c = threadIdx.x;
  float acc = 0.f;
  for (int n = 0; n < 32; n++) acc = __fadd_rn(acc, P[n * 256 + c]);
  M[c] = __fdiv_rn(acc, 100352.0f);
}

// mean combine (gemm layers): seq over 784 block partials (exact)
__global__ __launch_bounds__(256) void k_cmbG(const float* __restrict__ PM,
    float* __restrict__ M)
{
  int c = threadIdx.x;
  float acc = 0.f;
  for (int b = 0; b < 784; b++) acc = __fadd_rn(acc, PM[(size_t)b * 256 + c]);
  M[c] = __fdiv_rn(acc, 100352.0f);
}

// ===========================================================================
// VARIANCE — bit-exact numpy float32 pairwise order, parallelized.
// ===========================================================================

// var1: one block per (n,c) plane (NCHW int8); 256 thr = 32 leaves x 8 accs
__global__ __launch_bounds__(256) void k_var1(const signed char* __restrict__ c1,
    const float* __restrict__ a1, const float* __restrict__ M,
    float* __restrict__ PV)
{
  __shared__ float rr[256];
  __shared__ float lsm[32];
  int bid = blockIdx.x;
  int c = bid & 255;
  int t = threadIdx.x;
  int lf = t >> 3, j = t & 7;
  const int base = (lf >> 2) * 392 + (lf & 3) * 96;
  const int nb = ((lf & 3) == 3) ? 13 : 12;
  const signed char* pl = c1 + (size_t)bid * HWSZ + base + j;
  float av = a1[c], m = M[c];
  float r;
  {
    float v = (float)(int)pl[0];
    float tt = (v >= 0.f) ? v : __fmul_rn(av, v);
    float d = __fsub_rn(tt, m);
    r = __fmul_rn(d, d);
  }
  for (int b = 1; b < nb; b++) {
    float v = (float)(int)pl[8 * b];
    float tt = (v >= 0.f) ? v : __fmul_rn(av, v);
    float d = __fsub_rn(tt, m);
    r = __fadd_rn(r, __fmul_rn(d, d));
  }
  rr[t] = r;
  __syncthreads();
  if (j == 0) {
    const float* q = rr + lf * 8;
    lsm[lf] = __fadd_rn(
        __fadd_rn(__fadd_rn(q[0], q[1]), __fadd_rn(q[2], q[3])),
        __fadd_rn(__fadd_rn(q[4], q[5]), __fadd_rn(q[6], q[7])));
  }
  __syncthreads();
  if (t == 0) {
    float ch[8];
    #pragma unroll
    for (int q8 = 0; q8 < 8; q8++)
      ch[q8] = __fadd_rn(__fadd_rn(lsm[q8 * 4], lsm[q8 * 4 + 1]),
                         __fadd_rn(lsm[q8 * 4 + 2], lsm[q8 * 4 + 3]));
    float s0 = __fadd_rn(ch[0], ch[1]), s1 = __fadd_rn(ch[2], ch[3]);
    float s2 = __fadd_rn(ch[4], ch[5]), s3 = __fadd_rn(ch[6], ch[7]);
    PV[bid] = __fadd_rn(__fadd_rn(s0, s1), __fadd_rn(s2, s3));
  }
}

// var combine (layer1): seq over n plane sums, /100352, CR f32 rsqrt
__global__ __launch_bounds__(256) void k_vcmb(const float* __restrict__ PV,
    float* __restrict__ R)
{
  int c = threadIdx.x;
  float acc = 0.f;
  for (int n = 0; n < 32; n++) acc = __fadd_rn(acc, PV[n * 256 + c]);
  float v = __fdiv_rn(acc, 100352.0f);
  R[c] = (float)(1.0 / sqrt((double)__fadd_rn(v, 1e-5f)));
}

// varT: one block per (n, leaf) (NHWC bf16); 256 thr = 256 channels
__global__ __launch_bounds__(256) void k_varT(const unsigned short* __restrict__ tb,
    const float* __restrict__ M, float* __restrict__ PVL)
{
  int n = blockIdx.x >> 5, lf = blockIdx.x & 31;
  int c = threadIdx.x;
  const int base = (lf >> 2) * 392 + (lf & 3) * 96;
  const int nb = ((lf & 3) == 3) ? 13 : 12;
  const unsigned short* pl = tb + ((size_t)n * HWSZ + base) * 256 + c;
  float m = M[c];
  float r[8];
  #pragma unroll
  for (int j = 0; j < 8; j++) {
    float d = __fsub_rn(bf2f(pl[(size_t)j * 256]), m);
    r[j] = __fmul_rn(d, d);
  }
  for (int b = 1; b < nb; b++) {
    #pragma unroll
    for (int j = 0; j < 8; j++) {
      float d = __fsub_rn(bf2f(pl[(size_t)(8 * b + j) * 256]), m);
      r[j] = __fadd_rn(r[j], __fmul_rn(d, d));
    }
  }
  float lv = __fadd_rn(
      __fadd_rn(__fadd_rn(r[0], r[1]), __fadd_rn(r[2], r[3])),
      __fadd_rn(__fadd_rn(r[4], r[5]), __fadd_rn(r[6], r[7])));
  PVL[(size_t)blockIdx.x * 256 + c] = lv;
}

// varT combine: exact tree over 32 leaves, seq over n, /100352, CR rsqrt
__global__ __launch_bounds__(256) void k_vcmbT(const float* __restrict__ PVL,
    float* __restrict__ R)
{
  int c = threadIdx.x;
  float acc = 0.f;
  for (int n = 0; n < 32; n++) {
    float ch[8];
    #pragma unroll
    for (int q = 0; q < 8; q++) {
      const float* p = PVL + ((size_t)(n * 32 + q * 4)) * 256 + c;
      ch[q] = __fadd_rn(__fadd_rn(p[0], p[256]), __fadd_rn(p[512], p[768]));
    }
    float s0 = __fadd_rn(ch[0], ch[1]), s1 = __fadd_rn(ch[2], ch[3]);
    float s2 = __fadd_rn(ch[4], ch[5]), s3 = __fadd_rn(ch[6], ch[7]);
    float plane = __fadd_rn(__fadd_rn(s0, s1), __fadd_rn(s2, s3));
    acc = __fadd_rn(acc, plane);
  }
  float v = __fdiv_rn(acc, 100352.0f);
  R[c] = (float)(1.0 / sqrt((double)__fadd_rn(v, 1e-5f)));
}

// ---------------------------------------------------------------------------
// K2: apply1: SB = sign( ((t1-m)*r)*g + b + x ), f32-replica, NCHW->NHWC
// ---------------------------------------------------------------------------
__global__ __launch_bounds__(256) void k_apply1(const float* __restrict__ x,
    const signed char* __restrict__ c1, const float* __restrict__ a1,
    const float* __restrict__ M1, const float* __restrict__ R1,
    const float* __restrict__ g1, const float* __restrict__ b1,
    unsigned short* __restrict__ s1)
{
  __shared__ __align__(16) unsigned short ls[64 * 264];
  int bid = blockIdx.x;
  int n = bid / 49, pb = bid % 49;
  int px0 = pb * 64;
  int t = threadIdx.x;
  int lane = t & 63, crow = t >> 6;

  for (int j = 0; j < 64; j++) {
    int c = j * 4 + crow;
    size_t gidx = ((size_t)(n * 256 + c)) * HWSZ + px0 + lane;
    float xv = x[gidx];
    float v = (float)(int)c1[gidx];
    float av = a1[c];
    float t1 = (v >= 0.f) ? v : __fmul_rn(av, v);
    float xn = __fmul_rn(__fsub_rn(t1, M1[c]), R1[c]);
    float bn = __fadd_rn(__fmul_rn(xn, g1[c]), b1[c]);
    float o1 = __fadd_rn(bn, xv);
    ls[lane * 264 + c] = sgnf_bf16(o1);
  }
  __syncthreads();
  unsigned short* sp = s1 + ((size_t)(n * HWSZ + px0)) * 256;
  for (int j = 0; j < 8; j++) {
    int f = j * 256 + t;
    int px = f >> 5, c16 = f & 31;
    *(u16x8*)(sp + px * 256 + c16 * 8) = *(const u16x8*)(ls + px * 264 + c16 * 8);
  }
}

// ---------------------------------------------------------------------------
// K4: apply2: SB = sign( bn2(t2) + (bn1(t1)+x) ), f32-replica
// ---------------------------------------------------------------------------
__global__ __launch_bounds__(256) void k_apply2(const float* __restrict__ x,
    const signed char* __restrict__ c1, const unsigned short* __restrict__ t2,
    const float* __restrict__ a1,
    const float* __restrict__ M1, const float* __restrict__ R1,
    const float* __restrict__ g1, const float* __restrict__ b1,
    const float* __restrict__ M2, const float* __restrict__ R2,
    const float* __restrict__ g2, const float* __restrict__ b2,
    unsigned short* __restrict__ s2)
{
  __shared__ __align__(16) unsigned short lt[32 * 264];
  __shared__ __align__(16) unsigned short ls[32 * 264];
  int bid = blockIdx.x;
  int n = bid / 98, pb = bid % 98;
  int px0 = pb * 32;
  int t = threadIdx.x;

  const unsigned short* tp = t2 + ((size_t)(n * HWSZ + px0)) * 256;
  for (int j = 0; j < 4; j++) {
    int f = j * 256 + t;
    int px = f >> 5, c16 = f & 31;
    *(u16x8*)(lt + px * 264 + c16 * 8) = *(const u16x8*)(tp + px * 256 + c16 * 8);
  }
  __syncthreads();

  int lane = t & 31, crow = t >> 5;
  for (int j = 0; j < 32; j++) {
    int c = j * 8 + crow;
    size_t gidx = ((size_t)(n * 256 + c)) * HWSZ + px0 + lane;
    float xv = x[gidx];
    float v = (float)(int)c1[gidx];
    float av = a1[c];
    float t1 = (v >= 0.f) ? v : __fmul_rn(av, v);
    float xn1 = __fmul_rn(__fsub_rn(t1, M1[c]), R1[c]);
    float bn1v = __fadd_rn(__fmul_rn(xn1, g1[c]), b1[c]);
    float o1 = __fadd_rn(bn1v, xv);
    float t2v = bf2f(lt[lane * 264 + c]);
    float xn2 = __fmul_rn(__fsub_rn(t2v, M2[c]), R2[c]);
    float bn2v = __fadd_rn(__fmul_rn(xn2, g2[c]), b2[c]);
    float o2 = __fadd_rn(bn2v, o1);
    ls[lane * 264 + c] = sgnf_bf16(o2);
  }
  __syncthreads();
  unsigned short* sp = s2 + ((size_t)(n * HWSZ + px0)) * 256;
  for (int j = 0; j < 4; j++) {
    int f = j * 256 + t;
    int px = f >> 5, c16 = f & 31;
    *(u16x8*)(sp + px * 256 + c16 * 8) = *(const u16x8*)(ls + px * 264 + c16 * 8);
  }
}

// ---------------------------------------------------------------------------
// K6: apply3: SB = sign( bn3(t3) ), f32-replica, elementwise NHWC
// ---------------------------------------------------------------------------
__global__ __launch_bounds__(256) void k_apply3(const unsigned short* __restrict__ t3,
    const float* __restrict__ M3, const float* __restrict__ R3,
    const float* __restrict__ g3, const float* __restrict__ b3,
    unsigned short* __restrict__ s3)
{
  size_t idx = ((size_t)blockIdx.x * 256 + threadIdx.x) * 8;
  int c0 = (int)(idx & 255);
  u16x8 v = *(const u16x8*)(t3 + idx);
  u16x8 o;
  #pragma unroll
  for (int e = 0; e < 8; e++) {
    int c = c0 + e;
    float t = bf2f(v[e]);
    float xn = __fmul_rn(__fsub_rn(t, M3[c]), R3[c]);
    float bn = __fadd_rn(__fmul_rn(xn, g3[c]), b3[c]);
    o[e] = sgnf_bf16(bn);
  }
  *(u16x8*)(s3 + idx) = o;
}

// ---------------------------------------------------------------------------
// K8: final: out = bn4(t4) f32-replica, NHWC bf16 -> NCHW fp32
// ---------------------------------------------------------------------------
__global__ __launch_bounds__(256) void k_final(const unsigned short* __restrict__ t4,
    const float* __restrict__ M4, const float* __restrict__ R4,
    const float* __restrict__ g4, const float* __restrict__ b4,
    float* __restrict__ outp)
{
  __shared__ __align__(16) float lt[256 * 36];
  int bid = blockIdx.x;
  int n = bid / 98, pb = bid % 98;
  int px0 = pb * 32;
  int t = threadIdx.x;

  const unsigned short* tp = t4 + ((size_t)(n * HWSZ + px0)) * 256;
  for (int j = 0; j < 4; j++) {
    int f = j * 256 + t;
    int px = f >> 5, c16 = f & 31;
    u16x8 v = *(const u16x8*)(tp + px * 256 + c16 * 8);
    #pragma unroll
    for (int e = 0; e < 8; e++) {
      int c = c16 * 8 + e;
      float tv = bf2f(v[e]);
      float xn = __fmul_rn(__fsub_rn(tv, M4[c]), R4[c]);
      float bn = __fadd_rn(__fmul_rn(xn, g4[c]), b4[c]);
      lt[c * 36 + px] = bn;
    }
  }
  __syncthreads();
  for (int j = 0; j < 4; j++) {
    int f = j * 256 + t;
    int c = f >> 2, p8 = f & 3;
    f32x4 v0 = *(const f32x4*)(lt + c * 36 + p8 * 8);
    f32x4 v1 = *(const f32x4*)(lt + c * 36 + p8 * 8 + 4);
    float* op = outp + ((size_t)(n * 256 + c)) * HWSZ + px0 + p8 * 8;
    *(f32x4*)op = v0;
    *(f32x4*)(op + 4) = v1;
  }
}

// ---------------------------------------------------------------------------
// K3/5/7: GEMM: TB = prelu(SB x BS^T), exact ints via bf16 MFMA, padded LDS,
// + fused per-block column mean-partials (exact int f32 sums, order-free)
// ---------------------------------------------------------------------------
__global__ __launch_bounds__(512) void k_gemm(
    const unsigned short* __restrict__ sIn, const unsigned short* __restrict__ bsg,
    const float* __restrict__ aP, unsigned short* __restrict__ tOut,
    float* __restrict__ PM)
{
  __shared__ __align__(16) unsigned short As[128 * 72];
  __shared__ __align__(16) unsigned short Bs[256 * 72];
  __shared__ float red[8][4][16];
  const int t = threadIdx.x;
  const int lane = t & 63;
  const int wid = t >> 6;
  const int wm = wid >> 2, wn = wid & 3;
  const int lr = lane & 15, lk = lane >> 4;
  const int pix0 = blockIdx.x * 128;
  const unsigned short* Ap = sIn + (size_t)pix0 * 256;

  f32x4 acc[4][4];
  #pragma unroll
  for (int i = 0; i < 4; i++)
    #pragma unroll
    for (int j = 0; j < 4; j++)
      acc[i][j] = (f32x4){0.f, 0.f, 0.f, 0.f};

  for (int kt = 0; kt < 4; kt++) {
    const int k0 = kt * 64;
    if (kt) __syncthreads();
    #pragma unroll
    for (int j = 0; j < 2; j++) {
      int idx = j * 512 + t;
      int row = idx >> 3, kc = idx & 7;
      u16x8 v = *(const u16x8*)(Ap + (size_t)row * 256 + k0 + kc * 8);
      *(u16x8*)(As + row * 72 + kc * 8) = v;
    }
    #pragma unroll
    for (int j = 0; j < 4; j++) {
      int idx = j * 512 + t;
      int row = idx >> 3, kc = idx & 7;
      u16x8 v = *(const u16x8*)(bsg + (size_t)row * 256 + k0 + kc * 8);
      *(u16x8*)(Bs + row * 72 + kc * 8) = v;
    }
    __syncthreads();
    #pragma unroll
    for (int h = 0; h < 2; h++) {
      bf16x8 af[4], bfr[4];
      #pragma unroll
      for (int mf = 0; mf < 4; mf++)
        af[mf] = *(const bf16x8*)(As + (wm * 64 + mf * 16 + lr) * 72 + (h * 4 + lk) * 8);
      #pragma unroll
      for (int nf = 0; nf < 4; nf++)
        bfr[nf] = *(const bf16x8*)(Bs + (wn * 64 + nf * 16 + lr) * 72 + (h * 4 + lk) * 8);
      #pragma unroll
      for (int mf = 0; mf < 4; mf++)
        #pragma unroll
        for (int nf = 0; nf < 4; nf++)
          acc[mf][nf] = __builtin_amdgcn_mfma_f32_16x16x32_bf16(
              af[mf], bfr[nf], acc[mf][nf], 0, 0, 0);
    }
  }

  float csum[4];
  #pragma unroll
  for (int nf = 0; nf < 4; nf++) csum[nf] = 0.f;

  #pragma unroll
  for (int nf = 0; nf < 4; nf++) {
    int gcol = wn * 64 + nf * 16 + lr;
    float av = aP[gcol];
    #pragma unroll
    for (int mf = 0; mf < 4; mf++) {
      #pragma unroll
      for (int r = 0; r < 4; r++) {
        int grow = pix0 + wm * 64 + mf * 16 + lk * 4 + r;
        float u = acc[mf][nf][r];
        float tv = (u >= 0.f) ? u : __fmul_rn(av, u);   // exact quarter-ints
        tOut[(size_t)grow * 256 + gcol] = f2bf(tv);
        csum[nf] = __fadd_rn(csum[nf], tv);             // exact, order-free
      }
    }
  }
  #pragma unroll
  for (int nf = 0; nf < 4; nf++) {
    csum[nf] = __fadd_rn(csum[nf], __shfl_xor(csum[nf], 16));
    csum[nf] = __fadd_rn(csum[nf], __shfl_xor(csum[nf], 32));
  }
  if (lane < 16) {
    #pragma unroll
    for (int nf = 0; nf < 4; nf++) red[wid][nf][lane] = csum[nf];
  }
  __syncthreads();
  if (t < 256) {
    int wn2 = t >> 6, nf2 = (t >> 4) & 3, lr2 = t & 15;
    PM[(size_t)blockIdx.x * 256 + t] =
        __fadd_rn(red[wn2][nf2][lr2], red[wn2 + 4][nf2][lr2]);
  }
}

// ---------------------------------------------------------------------------
extern "C" void kernel_launch(void* const* d_in, const int* in_sizes, int n_in,
                              void* d_out, int out_size, void* d_ws, size_t ws_size,
                              hipStream_t stream)
{
  const float* x   = (const float*)d_in[0];
  const float* wdw = (const float*)d_in[1];
  const float* w1  = (const float*)d_in[2];
  const float* w2  = (const float*)d_in[3];
  const float* w3  = (const float*)d_in[4];
  const float* a1  = (const float*)d_in[5];
  const float* a2  = (const float*)d_in[6];
  const float* a3  = (const float*)d_in[7];
  const float* a4  = (const float*)d_in[8];
  const float* g1  = (const float*)d_in[9];
  const float* b1  = (const float*)d_in[10];
  const float* g2  = (const float*)d_in[11];
  const float* b2  = (const float*)d_in[12];
  const float* g3  = (const float*)d_in[13];
  const float* b3  = (const float*)d_in[14];
  const float* g4  = (const float*)d_in[15];
  const float* b4  = (const float*)d_in[16];

  char* ws = (char*)d_ws;
  unsigned short* SB  = (unsigned short*)ws;                  // 51,380,224 B
  unsigned short* TB  = (unsigned short*)(ws + 51380224);     // 51,380,224 B
  signed char*    c1  = (signed char*)(ws + 102760448);       // 25,690,112 B
  unsigned short* BS  = (unsigned short*)(ws + 128450560);    //    393,216 B
  float*          BIG = (float*)(ws + 128843776);             //  1,048,576 B (PM / P1 / PVL, time-shared)
  float*          PV  = (float*)(ws + 129892352);             //     32,768 B
  float*          MR  = (float*)(ws + 129925120);             //      8,192 B
  float*          outp = (float*)d_out;                       // fp32 NCHW

  float* P1  = BIG;   // [32][256] plane sums (layer1)
  float* PM  = BIG;   // [784][256] gemm block sums
  float* PVL = BIG;   // [1024][256] varT leaf sums
  float* M1 = MR;        float* R1 = MR + 256;
  float* M2 = MR + 512;  float* R2 = MR + 768;
  float* M3 = MR + 1024; float* R3 = MR + 1280;
  float* M4 = MR + 1536; float* R4 = MR + 1792;

  k_prepw <<<dim3(768),  dim3(256), 0, stream>>>(w1, w2, w3, BS);
  k_dwconv<<<dim3(8192), dim3(256), 0, stream>>>(x, wdw, a1, c1, P1);

  // BN1: fused mean partials, parallel np-ordered var, CR rsqrt
  k_cmb   <<<dim3(1),    dim3(256), 0, stream>>>(P1, M1);
  k_var1  <<<dim3(8192), dim3(256), 0, stream>>>(c1, a1, M1, PV);
  k_vcmb  <<<dim3(1),    dim3(256), 0, stream>>>(PV, R1);
  k_apply1<<<dim3(1568), dim3(256), 0, stream>>>(x, c1, a1, M1, R1, g1, b1, SB);

  // layer 2
  k_gemm  <<<dim3(784),  dim3(512), 0, stream>>>(SB, BS, a2, TB, PM);
  k_cmbG  <<<dim3(1),    dim3(256), 0, stream>>>(PM, M2);
  k_varT  <<<dim3(1024), dim3(256), 0, stream>>>(TB, M2, PVL);
  k_vcmbT <<<dim3(1),    dim3(256), 0, stream>>>(PVL, R2);
  k_apply2<<<dim3(3136), dim3(256), 0, stream>>>(x, c1, TB, a1,
                                                 M1, R1, g1, b1, M2, R2, g2, b2, SB);

  // layer 3
  k_gemm  <<<dim3(784),  dim3(512), 0, stream>>>(SB, BS + 65536, a3, TB, PM);
  k_cmbG  <<<dim3(1),    dim3(256), 0, stream>>>(PM, M3);
  k_varT  <<<dim3(1024), dim3(256), 0, stream>>>(TB, M3, PVL);
  k_vcmbT <<<dim3(1),    dim3(256), 0, stream>>>(PVL, R3);
  k_apply3<<<dim3(12544),dim3(256), 0, stream>>>(TB, M3, R3, g3, b3, SB);

  // layer 4
  k_gemm  <<<dim3(784),  dim3(512), 0, stream>>>(SB, BS + 131072, a4, TB, PM);
  k_cmbG  <<<dim3(1),    dim3(256), 0, stream>>>(PM, M4);
  k_varT  <<<dim3(1024), dim3(256), 0, stream>>>(TB, M4, PVL);
  k_vcmbT <<<dim3(1),    dim3(256), 0, stream>>>(PVL, R4);
  k_final <<<dim3(3136), dim3(256), 0, stream>>>(TB, M4, R4, g4, b4, outp);
}

// Round 12
// 546.142 us; speedup vs baseline: 5.8250x; 1.2324x over previous
//
#include <hip/hip_runtime.h>
#include <stdint.h>
#include <stddef.h>
#include <math.h>

#define HWSZ   3136        // 56*56
#define NPIX   100352      // 32*3136

typedef __attribute__((ext_vector_type(4))) float f32x4;
typedef __attribute__((ext_vector_type(8))) short bf16x8;
typedef __attribute__((ext_vector_type(8))) unsigned short u16x8;

__device__ __forceinline__ float bf2f(unsigned short u) {
  union { float f; unsigned int i; } v; v.i = ((unsigned int)u) << 16; return v.f;
}
__device__ __forceinline__ unsigned short f2bf(float f) {
  union { float f; unsigned int i; } v; v.f = f;
  return (unsigned short)((v.i + 0x7FFFu + ((v.i >> 16) & 1u)) >> 16);
}
__device__ __forceinline__ unsigned short sgnf_bf16(float v) {
  return (v > 0.f) ? 0x3F80u : ((v < 0.f) ? 0xBF80u : 0u);
}
__device__ __forceinline__ int isgn(float v) {
  return (v > 0.f) ? 1 : ((v < 0.f) ? -1 : 0);
}

// ---------------------------------------------------------------------------
// K0: weight prep: sign(w) as bf16, [o][c] layout
// ---------------------------------------------------------------------------
__global__ __launch_bounds__(256) void k_prepw(const float* __restrict__ w1,
    const float* __restrict__ w2, const float* __restrict__ w3,
    unsigned short* __restrict__ bs)
{
  int idx = blockIdx.x * 256 + threadIdx.x;
  int wsel = idx >> 16, rem = idx & 65535;
  const float* wp = (wsel == 0) ? w1 : ((wsel == 1) ? w2 : w3);
  float v = wp[rem];
  bs[idx] = sgnf_bf16(v);
}

// ---------------------------------------------------------------------------
// K1: depthwise 3x3 sign-conv -> c1 int8 + fused plane mean-partials.
// Vectorized f32x4 x-loads; LDS float sign-plane; packed uint c1 stores.
// ---------------------------------------------------------------------------
__global__ __launch_bounds__(256) void k_dwconv(const float* __restrict__ x,
    const float* __restrict__ wdw, const float* __restrict__ a1,
    signed char* __restrict__ c1, float* __restrict__ P1)
{
  __shared__ float sp[58 * 60];    // row r = h+1, col = w+2
  __shared__ float rs[4];
  int bid = blockIdx.x;            // n*256 + c
  int c = bid & 255;
  int t = threadIdx.x;
  const float* xp = x + (size_t)bid * HWSZ;

  for (int i = t; i < 58 * 60; i += 256) sp[i] = 0.f;
  __syncthreads();
  for (int q = t; q < 784; q += 256) {
    int h = q / 14, w0 = (q - h * 14) * 4;
    f32x4 v = *(const f32x4*)(xp + h * 56 + w0);
    float* d = sp + (h + 1) * 60 + (w0 + 2);
    d[0] = (float)isgn(v[0]);
    d[1] = (float)isgn(v[1]);
    d[2] = (float)isgn(v[2]);
    d[3] = (float)isgn(v[3]);
  }
  float wsf[9];
  #pragma unroll
  for (int i = 0; i < 9; i++) wsf[i] = (float)isgn(wdw[c * 9 + i]);
  float av = a1[c];
  __syncthreads();

  float lsum = 0.f;
  signed char* outp = c1 + (size_t)bid * HWSZ;
  for (int q = t; q < 784; q += 256) {
    int h = q / 14, w0 = (q - h * 14) * 4;
    float win[3][8];
    #pragma unroll
    for (int r = 0; r < 3; r++) {
      const float* rowp = sp + (h + r) * 60 + w0;
      *(f32x4*)(&win[r][0]) = *(const f32x4*)rowp;
      *(f32x4*)(&win[r][4]) = *(const f32x4*)(rowp + 4);
    }
    unsigned int pk = 0;
    #pragma unroll
    for (int j = 0; j < 4; j++) {
      float acc = 0.f;
      #pragma unroll
      for (int r = 0; r < 3; r++) {
        acc = fmaf(win[r][j + 1], wsf[r * 3 + 0], acc);
        acc = fmaf(win[r][j + 2], wsf[r * 3 + 1], acc);
        acc = fmaf(win[r][j + 3], wsf[r * 3 + 2], acc);
      }
      int ia = (int)acc;
      pk |= ((unsigned int)(unsigned char)(signed char)ia) << (8 * j);
      lsum += (acc >= 0.f) ? acc : av * acc;       // exact quarter-ints
    }
    *(unsigned int*)(void*)(outp + h * 56 + w0) = pk;
  }
  for (int o = 32; o > 0; o >>= 1) lsum += __shfl_xor(lsum, o);
  if ((t & 63) == 0) rs[t >> 6] = lsum;
  __syncthreads();
  if (t == 0) P1[bid] = ((rs[0] + rs[1]) + (rs[2] + rs[3]));
}

// mean combine (layer1): seq over 32 plane sums (exact), /100352 f32
__global__ __launch_bounds__(256) void k_cmb(const float* __restrict__ P,
    float* __restrict__ M)
{
  int c = threadIdx.x;
  float acc = 0.f;
  for (int n = 0; n < 32; n++) acc = __fadd_rn(acc, P[n * 256 + c]);
  M[c] = __fdiv_rn(acc, 100352.0f);
}

// mean combine (gemm layers): seq over 784 block partials (exact)
__global__ __launch_bounds__(256) void k_cmbG(const float* __restrict__ PM,
    float* __restrict__ M)
{
  int c = threadIdx.x;
  float acc = 0.f;
  for (int b = 0; b < 784; b++) acc = __fadd_rn(acc, PM[(size_t)b * 256 + c]);
  M[c] = __fdiv_rn(acc, 100352.0f);
}

// ===========================================================================
// VARIANCE — bit-exact numpy float32 pairwise order, parallelized.
// ===========================================================================

// var1: one block per (n,c) plane (NCHW int8); 256 thr = 32 leaves x 8 accs
__global__ __launch_bounds__(256) void k_var1(const signed char* __restrict__ c1,
    const float* __restrict__ a1, const float* __restrict__ M,
    float* __restrict__ PV)
{
  __shared__ float rr[256];
  __shared__ float lsm[32];
  int bid = blockIdx.x;
  int c = bid & 255;
  int t = threadIdx.x;
  int lf = t >> 3, j = t & 7;
  const int base = (lf >> 2) * 392 + (lf & 3) * 96;
  const int nb = ((lf & 3) == 3) ? 13 : 12;
  const signed char* pl = c1 + (size_t)bid * HWSZ + base + j;
  float av = a1[c], m = M[c];
  float r;
  {
    float v = (float)(int)pl[0];
    float tt = (v >= 0.f) ? v : __fmul_rn(av, v);
    float d = __fsub_rn(tt, m);
    r = __fmul_rn(d, d);
  }
  for (int b = 1; b < nb; b++) {
    float v = (float)(int)pl[8 * b];
    float tt = (v >= 0.f) ? v : __fmul_rn(av, v);
    float d = __fsub_rn(tt, m);
    r = __fadd_rn(r, __fmul_rn(d, d));
  }
  rr[t] = r;
  __syncthreads();
  if (j == 0) {
    const float* q = rr + lf * 8;
    lsm[lf] = __fadd_rn(
        __fadd_rn(__fadd_rn(q[0], q[1]), __fadd_rn(q[2], q[3])),
        __fadd_rn(__fadd_rn(q[4], q[5]), __fadd_rn(q[6], q[7])));
  }
  __syncthreads();
  if (t == 0) {
    float ch[8];
    #pragma unroll
    for (int q8 = 0; q8 < 8; q8++)
      ch[q8] = __fadd_rn(__fadd_rn(lsm[q8 * 4], lsm[q8 * 4 + 1]),
                         __fadd_rn(lsm[q8 * 4 + 2], lsm[q8 * 4 + 3]));
    float s0 = __fadd_rn(ch[0], ch[1]), s1 = __fadd_rn(ch[2], ch[3]);
    float s2 = __fadd_rn(ch[4], ch[5]), s3 = __fadd_rn(ch[6], ch[7]);
    PV[bid] = __fadd_rn(__fadd_rn(s0, s1), __fadd_rn(s2, s3));
  }
}

// var combine (layer1): seq over n plane sums, /100352, CR f32 rsqrt
__global__ __launch_bounds__(256) void k_vcmb(const float* __restrict__ PV,
    float* __restrict__ R)
{
  int c = threadIdx.x;
  float acc = 0.f;
  for (int n = 0; n < 32; n++) acc = __fadd_rn(acc, PV[n * 256 + c]);
  float v = __fdiv_rn(acc, 100352.0f);
  R[c] = (float)(1.0 / sqrt((double)__fadd_rn(v, 1e-5f)));
}

// varT: one block per (n, leaf) (NHWC bf16); 256 thr = 256 channels
__global__ __launch_bounds__(256) void k_varT(const unsigned short* __restrict__ tb,
    const float* __restrict__ M, float* __restrict__ PVL)
{
  int n = blockIdx.x >> 5, lf = blockIdx.x & 31;
  int c = threadIdx.x;
  const int base = (lf >> 2) * 392 + (lf & 3) * 96;
  const int nb = ((lf & 3) == 3) ? 13 : 12;
  const unsigned short* pl = tb + ((size_t)n * HWSZ + base) * 256 + c;
  float m = M[c];
  float r[8];
  #pragma unroll
  for (int j = 0; j < 8; j++) {
    float d = __fsub_rn(bf2f(pl[(size_t)j * 256]), m);
    r[j] = __fmul_rn(d, d);
  }
  for (int b = 1; b < nb; b++) {
    #pragma unroll
    for (int j = 0; j < 8; j++) {
      float d = __fsub_rn(bf2f(pl[(size_t)(8 * b + j) * 256]), m);
      r[j] = __fadd_rn(r[j], __fmul_rn(d, d));
    }
  }
  float lv = __fadd_rn(
      __fadd_rn(__fadd_rn(r[0], r[1]), __fadd_rn(r[2], r[3])),
      __fadd_rn(__fadd_rn(r[4], r[5]), __fadd_rn(r[6], r[7])));
  PVL[(size_t)blockIdx.x * 256 + c] = lv;
}

// varT combine: exact tree over 32 leaves, seq over n, /100352, CR rsqrt
__global__ __launch_bounds__(256) void k_vcmbT(const float* __restrict__ PVL,
    float* __restrict__ R)
{
  int c = threadIdx.x;
  float acc = 0.f;
  for (int n = 0; n < 32; n++) {
    float ch[8];
    #pragma unroll
    for (int q = 0; q < 8; q++) {
      const float* p = PVL + ((size_t)(n * 32 + q * 4)) * 256 + c;
      ch[q] = __fadd_rn(__fadd_rn(p[0], p[256]), __fadd_rn(p[512], p[768]));
    }
    float s0 = __fadd_rn(ch[0], ch[1]), s1 = __fadd_rn(ch[2], ch[3]);
    float s2 = __fadd_rn(ch[4], ch[5]), s3 = __fadd_rn(ch[6], ch[7]);
    float plane = __fadd_rn(__fadd_rn(s0, s1), __fadd_rn(s2, s3));
    acc = __fadd_rn(acc, plane);
  }
  float v = __fdiv_rn(acc, 100352.0f);
  R[c] = (float)(1.0 / sqrt((double)__fadd_rn(v, 1e-5f)));
}

// ---------------------------------------------------------------------------
// K2: apply1: SB = sign( ((t1-m)*r)*g + b + x ), 32-px tile (16.9 KB LDS)
// ---------------------------------------------------------------------------
__global__ __launch_bounds__(256) void k_apply1(const float* __restrict__ x,
    const signed char* __restrict__ c1, const float* __restrict__ a1,
    const float* __restrict__ M1, const float* __restrict__ R1,
    const float* __restrict__ g1, const float* __restrict__ b1,
    unsigned short* __restrict__ s1)
{
  __shared__ __align__(16) unsigned short ls[32 * 264];
  int bid = blockIdx.x;
  int n = bid / 98, pb = bid % 98;
  int px0 = pb * 32;
  int t = threadIdx.x;
  int lane = t & 31, crow = t >> 5;

  for (int j = 0; j < 32; j++) {
    int c = j * 8 + crow;
    size_t gidx = ((size_t)(n * 256 + c)) * HWSZ + px0 + lane;
    float xv = x[gidx];
    float v = (float)(int)c1[gidx];
    float av = a1[c];
    float t1 = (v >= 0.f) ? v : __fmul_rn(av, v);
    float xn = __fmul_rn(__fsub_rn(t1, M1[c]), R1[c]);
    float bn = __fadd_rn(__fmul_rn(xn, g1[c]), b1[c]);
    float o1 = __fadd_rn(bn, xv);
    ls[lane * 264 + c] = sgnf_bf16(o1);
  }
  __syncthreads();
  unsigned short* sp = s1 + ((size_t)(n * HWSZ + px0)) * 256;
  for (int j = 0; j < 4; j++) {
    int f = j * 256 + t;
    int px = f >> 5, c16 = f & 31;
    *(u16x8*)(sp + px * 256 + c16 * 8) = *(const u16x8*)(ls + px * 264 + c16 * 8);
  }
}

// ---------------------------------------------------------------------------
// K4: apply2: SB = sign( bn2(t2) + (bn1(t1)+x) ) — IN-PLACE single LDS buffer
// (slot (px,c) is read then written by the same thread -> no hazard; 16.9 KB)
// ---------------------------------------------------------------------------
__global__ __launch_bounds__(256) void k_apply2(const float* __restrict__ x,
    const signed char* __restrict__ c1, const unsigned short* __restrict__ t2,
    const float* __restrict__ a1,
    const float* __restrict__ M1, const float* __restrict__ R1,
    const float* __restrict__ g1, const float* __restrict__ b1,
    const float* __restrict__ M2, const float* __restrict__ R2,
    const float* __restrict__ g2, const float* __restrict__ b2,
    unsigned short* __restrict__ s2)
{
  __shared__ __align__(16) unsigned short lb[32 * 264];
  int bid = blockIdx.x;
  int n = bid / 98, pb = bid % 98;
  int px0 = pb * 32;
  int t = threadIdx.x;

  const unsigned short* tp = t2 + ((size_t)(n * HWSZ + px0)) * 256;
  for (int j = 0; j < 4; j++) {
    int f = j * 256 + t;
    int px = f >> 5, c16 = f & 31;
    *(u16x8*)(lb + px * 264 + c16 * 8) = *(const u16x8*)(tp + px * 256 + c16 * 8);
  }
  __syncthreads();

  int lane = t & 31, crow = t >> 5;
  for (int j = 0; j < 32; j++) {
    int c = j * 8 + crow;
    size_t gidx = ((size_t)(n * 256 + c)) * HWSZ + px0 + lane;
    float xv = x[gidx];
    float v = (float)(int)c1[gidx];
    float av = a1[c];
    float t1 = (v >= 0.f) ? v : __fmul_rn(av, v);
    float xn1 = __fmul_rn(__fsub_rn(t1, M1[c]), R1[c]);
    float bn1v = __fadd_rn(__fmul_rn(xn1, g1[c]), b1[c]);
    float o1 = __fadd_rn(bn1v, xv);
    float t2v = bf2f(lb[lane * 264 + c]);
    float xn2 = __fmul_rn(__fsub_rn(t2v, M2[c]), R2[c]);
    float bn2v = __fadd_rn(__fmul_rn(xn2, g2[c]), b2[c]);
    float o2 = __fadd_rn(bn2v, o1);
    lb[lane * 264 + c] = sgnf_bf16(o2);
  }
  __syncthreads();
  unsigned short* sp = s2 + ((size_t)(n * HWSZ + px0)) * 256;
  for (int j = 0; j < 4; j++) {
    int f = j * 256 + t;
    int px = f >> 5, c16 = f & 31;
    *(u16x8*)(sp + px * 256 + c16 * 8) = *(const u16x8*)(lb + px * 264 + c16 * 8);
  }
}

// ---------------------------------------------------------------------------
// K6: apply3: SB = sign( bn3(t3) ), f32-replica, elementwise NHWC
// ---------------------------------------------------------------------------
__global__ __launch_bounds__(256) void k_apply3(const unsigned short* __restrict__ t3,
    const float* __restrict__ M3, const float* __restrict__ R3,
    const float* __restrict__ g3, const float* __restrict__ b3,
    unsigned short* __restrict__ s3)
{
  size_t idx = ((size_t)blockIdx.x * 256 + threadIdx.x) * 8;
  int c0 = (int)(idx & 255);
  u16x8 v = *(const u16x8*)(t3 + idx);
  u16x8 o;
  #pragma unroll
  for (int e = 0; e < 8; e++) {
    int c = c0 + e;
    float t = bf2f(v[e]);
    float xn = __fmul_rn(__fsub_rn(t, M3[c]), R3[c]);
    float bn = __fadd_rn(__fmul_rn(xn, g3[c]), b3[c]);
    o[e] = sgnf_bf16(bn);
  }
  *(u16x8*)(s3 + idx) = o;
}

// ---------------------------------------------------------------------------
// K8: final: out = bn4(t4), NHWC bf16 -> NCHW fp32. 16-px tile, [px][260]
// layout (16.6 KB -> 9 blocks/CU); vector LDS writes, scalar reads (2-way).
// ---------------------------------------------------------------------------
__global__ __launch_bounds__(256) void k_final(const unsigned short* __restrict__ t4,
    const float* __restrict__ M4, const float* __restrict__ R4,
    const float* __restrict__ g4, const float* __restrict__ b4,
    float* __restrict__ outp)
{
  __shared__ __align__(16) float lt[16 * 260];
  int bid = blockIdx.x;
  int n = bid / 196, pb = bid % 196;
  int px0 = pb * 16;
  int t = threadIdx.x;

  const unsigned short* tp = t4 + ((size_t)(n * HWSZ + px0)) * 256;
  for (int j = 0; j < 2; j++) {
    int f = j * 256 + t;
    int px = f >> 5, c16 = f & 31;
    u16x8 v = *(const u16x8*)(tp + px * 256 + c16 * 8);
    f32x4 o0, o1;
    #pragma unroll
    for (int e = 0; e < 4; e++) {
      int c = c16 * 8 + e;
      float tv = bf2f(v[e]);
      float xn = __fmul_rn(__fsub_rn(tv, M4[c]), R4[c]);
      o0[e] = __fadd_rn(__fmul_rn(xn, g4[c]), b4[c]);
    }
    #pragma unroll
    for (int e = 0; e < 4; e++) {
      int c = c16 * 8 + 4 + e;
      float tv = bf2f(v[4 + e]);
      float xn = __fmul_rn(__fsub_rn(tv, M4[c]), R4[c]);
      o1[e] = __fadd_rn(__fmul_rn(xn, g4[c]), b4[c]);
    }
    *(f32x4*)(lt + px * 260 + c16 * 8) = o0;
    *(f32x4*)(lt + px * 260 + c16 * 8 + 4) = o1;
  }
  __syncthreads();
  for (int j = 0; j < 4; j++) {
    int f = j * 256 + t;
    int c = f >> 2, q = f & 3;
    f32x4 v;
    #pragma unroll
    for (int e = 0; e < 4; e++) v[e] = lt[(q * 4 + e) * 260 + c];
    *(f32x4*)(outp + ((size_t)(n * 256 + c)) * HWSZ + px0 + q * 4) = v;
  }
}

// ---------------------------------------------------------------------------
// K3/5/7: GEMM: TB = prelu(SB x BS^T), exact ints via bf16 MFMA, padded LDS,
// + fused per-block column mean-partials (exact int f32 sums, order-free)
// ---------------------------------------------------------------------------
__global__ __launch_bounds__(512) void k_gemm(
    const unsigned short* __restrict__ sIn, const unsigned short* __restrict__ bsg,
    const float* __restrict__ aP, unsigned short* __restrict__ tOut,
    float* __restrict__ PM)
{
  __shared__ __align__(16) unsigned short As[128 * 72];
  __shared__ __align__(16) unsigned short Bs[256 * 72];
  __shared__ float red[8][4][16];
  const int t = threadIdx.x;
  const int lane = t & 63;
  const int wid = t >> 6;
  const int wm = wid >> 2, wn = wid & 3;
  const int lr = lane & 15, lk = lane >> 4;
  const int pix0 = blockIdx.x * 128;
  const unsigned short* Ap = sIn + (size_t)pix0 * 256;

  f32x4 acc[4][4];
  #pragma unroll
  for (int i = 0; i < 4; i++)
    #pragma unroll
    for (int j = 0; j < 4; j++)
      acc[i][j] = (f32x4){0.f, 0.f, 0.f, 0.f};

  for (int kt = 0; kt < 4; kt++) {
    const int k0 = kt * 64;
    if (kt) __syncthreads();
    #pragma unroll
    for (int j = 0; j < 2; j++) {
      int idx = j * 512 + t;
      int row = idx >> 3, kc = idx & 7;
      u16x8 v = *(const u16x8*)(Ap + (size_t)row * 256 + k0 + kc * 8);
      *(u16x8*)(As + row * 72 + kc * 8) = v;
    }
    #pragma unroll
    for (int j = 0; j < 4; j++) {
      int idx = j * 512 + t;
      int row = idx >> 3, kc = idx & 7;
      u16x8 v = *(const u16x8*)(bsg + (size_t)row * 256 + k0 + kc * 8);
      *(u16x8*)(Bs + row * 72 + kc * 8) = v;
    }
    __syncthreads();
    #pragma unroll
    for (int h = 0; h < 2; h++) {
      bf16x8 af[4], bfr[4];
      #pragma unroll
      for (int mf = 0; mf < 4; mf++)
        af[mf] = *(const bf16x8*)(As + (wm * 64 + mf * 16 + lr) * 72 + (h * 4 + lk) * 8);
      #pragma unroll
      for (int nf = 0; nf < 4; nf++)
        bfr[nf] = *(const bf16x8*)(Bs + (wn * 64 + nf * 16 + lr) * 72 + (h * 4 + lk) * 8);
      #pragma unroll
      for (int mf = 0; mf < 4; mf++)
        #pragma unroll
        for (int nf = 0; nf < 4; nf++)
          acc[mf][nf] = __builtin_amdgcn_mfma_f32_16x16x32_bf16(
              af[mf], bfr[nf], acc[mf][nf], 0, 0, 0);
    }
  }

  float csum[4];
  #pragma unroll
  for (int nf = 0; nf < 4; nf++) csum[nf] = 0.f;

  #pragma unroll
  for (int nf = 0; nf < 4; nf++) {
    int gcol = wn * 64 + nf * 16 + lr;
    float av = aP[gcol];
    #pragma unroll
    for (int mf = 0; mf < 4; mf++) {
      #pragma unroll
      for (int r = 0; r < 4; r++) {
        int grow = pix0 + wm * 64 + mf * 16 + lk * 4 + r;
        float u = acc[mf][nf][r];
        float tv = (u >= 0.f) ? u : __fmul_rn(av, u);   // exact quarter-ints
        tOut[(size_t)grow * 256 + gcol] = f2bf(tv);
        csum[nf] = __fadd_rn(csum[nf], tv);             // exact, order-free
      }
    }
  }
  #pragma unroll
  for (int nf = 0; nf < 4; nf++) {
    csum[nf] = __fadd_rn(csum[nf], __shfl_xor(csum[nf], 16));
    csum[nf] = __fadd_rn(csum[nf], __shfl_xor(csum[nf], 32));
  }
  if (lane < 16) {
    #pragma unroll
    for (int nf = 0; nf < 4; nf++) red[wid][nf][lane] = csum[nf];
  }
  __syncthreads();
  if (t < 256) {
    int wn2 = t >> 6, nf2 = (t >> 4) & 3, lr2 = t & 15;
    PM[(size_t)blockIdx.x * 256 + t] =
        __fadd_rn(red[wn2][nf2][lr2], red[wn2 + 4][nf2][lr2]);
  }
}

// ---------------------------------------------------------------------------
extern "C" void kernel_launch(void* const* d_in, const int* in_sizes, int n_in,
                              void* d_out, int out_size, void* d_ws, size_t ws_size,
                              hipStream_t stream)
{
  const float* x   = (const float*)d_in[0];
  const float* wdw = (const float*)d_in[1];
  const float* w1  = (const float*)d_in[2];
  const float* w2  = (const float*)d_in[3];
  const float* w3  = (const float*)d_in[4];
  const float* a1  = (const float*)d_in[5];
  const float* a2  = (const float*)d_in[6];
  const float* a3  = (const float*)d_in[7];
  const float* a4  = (const float*)d_in[8];
  const float* g1  = (const float*)d_in[9];
  const float* b1  = (const float*)d_in[10];
  const float* g2  = (const float*)d_in[11];
  const float* b2  = (const float*)d_in[12];
  const float* g3  = (const float*)d_in[13];
  const float* b3  = (const float*)d_in[14];
  const float* g4  = (const float*)d_in[15];
  const float* b4  = (const float*)d_in[16];

  char* ws = (char*)d_ws;
  unsigned short* SB  = (unsigned short*)ws;                  // 51,380,224 B
  unsigned short* TB  = (unsigned short*)(ws + 51380224);     // 51,380,224 B
  signed char*    c1  = (signed char*)(ws + 102760448);       // 25,690,112 B
  unsigned short* BS  = (unsigned short*)(ws + 128450560);    //    393,216 B
  float*          BIG = (float*)(ws + 128843776);             //  1,048,576 B (PM / P1 / PVL)
  float*          PV  = (float*)(ws + 129892352);             //     32,768 B
  float*          MR  = (float*)(ws + 129925120);             //      8,192 B
  float*          outp = (float*)d_out;                       // fp32 NCHW

  float* P1  = BIG;   // [32][256] plane sums (layer1)
  float* PM  = BIG;   // [784][256] gemm block sums
  float* PVL = BIG;   // [1024][256] varT leaf sums
  float* M1 = MR;        float* R1 = MR + 256;
  float* M2 = MR + 512;  float* R2 = MR + 768;
  float* M3 = MR + 1024; float* R3 = MR + 1280;
  float* M4 = MR + 1536; float* R4 = MR + 1792;

  k_prepw <<<dim3(768),  dim3(256), 0, stream>>>(w1, w2, w3, BS);
  k_dwconv<<<dim3(8192), dim3(256), 0, stream>>>(x, wdw, a1, c1, P1);

  // BN1: fused mean partials, parallel np-ordered var, CR rsqrt
  k_cmb   <<<dim3(1),    dim3(256), 0, stream>>>(P1, M1);
  k_var1  <<<dim3(8192), dim3(256), 0, stream>>>(c1, a1, M1, PV);
  k_vcmb  <<<dim3(1),    dim3(256), 0, stream>>>(PV, R1);
  k_apply1<<<dim3(3136), dim3(256), 0, stream>>>(x, c1, a1, M1, R1, g1, b1, SB);

  // layer 2
  k_gemm  <<<dim3(784),  dim3(512), 0, stream>>>(SB, BS, a2, TB, PM);
  k_cmbG  <<<dim3(1),    dim3(256), 0, stream>>>(PM, M2);
  k_varT  <<<dim3(1024), dim3(256), 0, stream>>>(TB, M2, PVL);
  k_vcmbT <<<dim3(1),    dim3(256), 0, stream>>>(PVL, R2);
  k_apply2<<<dim3(3136), dim3(256), 0, stream>>>(x, c1, TB, a1,
                                                 M1, R1, g1, b1, M2, R2, g2, b2, SB);

  // layer 3
  k_gemm  <<<dim3(784),  dim3(512), 0, stream>>>(SB, BS + 65536, a3, TB, PM);
  k_cmbG  <<<dim3(1),    dim3(256), 0, stream>>>(PM, M3);
  k_varT  <<<dim3(1024), dim3(256), 0, stream>>>(TB, M3, PVL);
  k_vcmbT <<<dim3(1),    dim3(256), 0, stream>>>(PVL, R3);
  k_apply3<<<dim3(12544),dim3(256), 0, stream>>>(TB, M3, R3, g3, b3, SB);

  // layer 4
  k_gemm  <<<dim3(784),  dim3(512), 0, stream>>>(SB, BS + 131072, a4, TB, PM);
  k_cmbG  <<<dim3(1),    dim3(256), 0, stream>>>(PM, M4);
  k_varT  <<<dim3(1024), dim3(256), 0, stream>>>(TB, M4, PVL);
  k_vcmbT <<<dim3(1),    dim3(256), 0, stream>>>(PVL, R4);
  k_final <<<dim3(6272), dim3(256), 0, stream>>>(TB, M4, R4, g4, b4, outp);
}

// Round 13
// 509.470 us; speedup vs baseline: 6.2442x; 1.0720x over previous
//
#include <hip/hip_runtime.h>
#include <stdint.h>
#include <stddef.h>
#include <math.h>

#define HWSZ   3136        // 56*56
#define NPIX   100352      // 32*3136

typedef __attribute__((ext_vector_type(4))) float f32x4;
typedef __attribute__((ext_vector_type(8))) short bf16x8;
typedef __attribute__((ext_vector_type(8))) unsigned short u16x8;

__device__ __forceinline__ float bf2f(unsigned short u) {
  union { float f; unsigned int i; } v; v.i = ((unsigned int)u) << 16; return v.f;
}
__device__ __forceinline__ unsigned short f2bf(float f) {
  union { float f; unsigned int i; } v; v.f = f;
  return (unsigned short)((v.i + 0x7FFFu + ((v.i >> 16) & 1u)) >> 16);
}
__device__ __forceinline__ unsigned short sgnf_bf16(float v) {
  return (v > 0.f) ? 0x3F80u : ((v < 0.f) ? 0xBF80u : 0u);
}
__device__ __forceinline__ int isgn(float v) {
  return (v > 0.f) ? 1 : ((v < 0.f) ? -1 : 0);
}

// ---------------------------------------------------------------------------
// K0: weight prep: sign(w) as bf16, [o][c] layout
// ---------------------------------------------------------------------------
__global__ __launch_bounds__(256) void k_prepw(const float* __restrict__ w1,
    const float* __restrict__ w2, const float* __restrict__ w3,
    unsigned short* __restrict__ bs)
{
  int idx = blockIdx.x * 256 + threadIdx.x;
  int wsel = idx >> 16, rem = idx & 65535;
  const float* wp = (wsel == 0) ? w1 : ((wsel == 1) ? w2 : w3);
  float v = wp[rem];
  bs[idx] = sgnf_bf16(v);
}

// ---------------------------------------------------------------------------
// K1: depthwise 3x3 sign-conv -> c1 int8 + fused plane mean-partials.
// ---------------------------------------------------------------------------
__global__ __launch_bounds__(256) void k_dwconv(const float* __restrict__ x,
    const float* __restrict__ wdw, const float* __restrict__ a1,
    signed char* __restrict__ c1, float* __restrict__ P1)
{
  __shared__ float sp[58 * 60];    // row r = h+1, col = w+2
  __shared__ float rs[4];
  int bid = blockIdx.x;            // n*256 + c
  int c = bid & 255;
  int t = threadIdx.x;
  const float* xp = x + (size_t)bid * HWSZ;

  for (int i = t; i < 58 * 60; i += 256) sp[i] = 0.f;
  __syncthreads();
  for (int q = t; q < 784; q += 256) {
    int h = q / 14, w0 = (q - h * 14) * 4;
    f32x4 v = *(const f32x4*)(xp + h * 56 + w0);
    float* d = sp + (h + 1) * 60 + (w0 + 2);
    d[0] = (float)isgn(v[0]);
    d[1] = (float)isgn(v[1]);
    d[2] = (float)isgn(v[2]);
    d[3] = (float)isgn(v[3]);
  }
  float wsf[9];
  #pragma unroll
  for (int i = 0; i < 9; i++) wsf[i] = (float)isgn(wdw[c * 9 + i]);
  float av = a1[c];
  __syncthreads();

  float lsum = 0.f;
  signed char* outp = c1 + (size_t)bid * HWSZ;
  for (int q = t; q < 784; q += 256) {
    int h = q / 14, w0 = (q - h * 14) * 4;
    float win[3][8];
    #pragma unroll
    for (int r = 0; r < 3; r++) {
      const float* rowp = sp + (h + r) * 60 + w0;
      *(f32x4*)(&win[r][0]) = *(const f32x4*)rowp;
      *(f32x4*)(&win[r][4]) = *(const f32x4*)(rowp + 4);
    }
    unsigned int pk = 0;
    #pragma unroll
    for (int j = 0; j < 4; j++) {
      float acc = 0.f;
      #pragma unroll
      for (int r = 0; r < 3; r++) {
        acc = fmaf(win[r][j + 1], wsf[r * 3 + 0], acc);
        acc = fmaf(win[r][j + 2], wsf[r * 3 + 1], acc);
        acc = fmaf(win[r][j + 3], wsf[r * 3 + 2], acc);
      }
      int ia = (int)acc;
      pk |= ((unsigned int)(unsigned char)(signed char)ia) << (8 * j);
      lsum += (acc >= 0.f) ? acc : av * acc;       // exact quarter-ints
    }
    *(unsigned int*)(void*)(outp + h * 56 + w0) = pk;
  }
  for (int o = 32; o > 0; o >>= 1) lsum += __shfl_xor(lsum, o);
  if ((t & 63) == 0) rs[t >> 6] = lsum;
  __syncthreads();
  if (t == 0) P1[bid] = ((rs[0] + rs[1]) + (rs[2] + rs[3]));
}

// mean combine (layer1): seq over 32 plane sums (exact), /100352 f32
__global__ __launch_bounds__(256) void k_cmb(const float* __restrict__ P,
    float* __restrict__ M)
{
  int c = threadIdx.x;
  float acc = 0.f;
  for (int n = 0; n < 32; n++) acc = __fadd_rn(acc, P[n * 256 + c]);
  M[c] = __fdiv_rn(acc, 100352.0f);
}

// mean combine (gemm layers): seq over 784 block partials (exact)
__global__ __launch_bounds__(256) void k_cmbG(const float* __restrict__ PM,
    float* __restrict__ M)
{
  int c = threadIdx.x;
  float acc = 0.f;
  for (int b = 0; b < 784; b++) acc = __fadd_rn(acc, PM[(size_t)b * 256 + c]);
  M[c] = __fdiv_rn(acc, 100352.0f);
}

// ===========================================================================
// VARIANCE — bit-exact numpy float32 pairwise order, parallelized.
// ===========================================================================

// var1: one block per (n,c) plane (NCHW int8); 256 thr = 32 leaves x 8 accs
__global__ __launch_bounds__(256) void k_var1(const signed char* __restrict__ c1,
    const float* __restrict__ a1, const float* __restrict__ M,
    float* __restrict__ PV)
{
  __shared__ float rr[256];
  __shared__ float lsm[32];
  int bid = blockIdx.x;
  int c = bid & 255;
  int t = threadIdx.x;
  int lf = t >> 3, j = t & 7;
  const int base = (lf >> 2) * 392 + (lf & 3) * 96;
  const int nb = ((lf & 3) == 3) ? 13 : 12;
  const signed char* pl = c1 + (size_t)bid * HWSZ + base + j;
  float av = a1[c], m = M[c];
  float r;
  {
    float v = (float)(int)pl[0];
    float tt = (v >= 0.f) ? v : __fmul_rn(av, v);
    float d = __fsub_rn(tt, m);
    r = __fmul_rn(d, d);
  }
  for (int b = 1; b < nb; b++) {
    float v = (float)(int)pl[8 * b];
    float tt = (v >= 0.f) ? v : __fmul_rn(av, v);
    float d = __fsub_rn(tt, m);
    r = __fadd_rn(r, __fmul_rn(d, d));
  }
  rr[t] = r;
  __syncthreads();
  if (j == 0) {
    const float* q = rr + lf * 8;
    lsm[lf] = __fadd_rn(
        __fadd_rn(__fadd_rn(q[0], q[1]), __fadd_rn(q[2], q[3])),
        __fadd_rn(__fadd_rn(q[4], q[5]), __fadd_rn(q[6], q[7])));
  }
  __syncthreads();
  if (t == 0) {
    float ch[8];
    #pragma unroll
    for (int q8 = 0; q8 < 8; q8++)
      ch[q8] = __fadd_rn(__fadd_rn(lsm[q8 * 4], lsm[q8 * 4 + 1]),
                         __fadd_rn(lsm[q8 * 4 + 2], lsm[q8 * 4 + 3]));
    float s0 = __fadd_rn(ch[0], ch[1]), s1 = __fadd_rn(ch[2], ch[3]);
    float s2 = __fadd_rn(ch[4], ch[5]), s3 = __fadd_rn(ch[6], ch[7]);
    PV[bid] = __fadd_rn(__fadd_rn(s0, s1), __fadd_rn(s2, s3));
  }
}

// var combine (layer1): seq over n plane sums, /100352, CR f32 rsqrt
__global__ __launch_bounds__(256) void k_vcmb(const float* __restrict__ PV,
    float* __restrict__ R)
{
  int c = threadIdx.x;
  float acc = 0.f;
  for (int n = 0; n < 32; n++) acc = __fadd_rn(acc, PV[n * 256 + c]);
  float v = __fdiv_rn(acc, 100352.0f);
  R[c] = (float)(1.0 / sqrt((double)__fadd_rn(v, 1e-5f)));
}

// varT: one block per (n, leaf) (NHWC bf16); 256 thr = 256 channels
__global__ __launch_bounds__(256) void k_varT(const unsigned short* __restrict__ tb,
    const float* __restrict__ M, float* __restrict__ PVL)
{
  int n = blockIdx.x >> 5, lf = blockIdx.x & 31;
  int c = threadIdx.x;
  const int base = (lf >> 2) * 392 + (lf & 3) * 96;
  const int nb = ((lf & 3) == 3) ? 13 : 12;
  const unsigned short* pl = tb + ((size_t)n * HWSZ + base) * 256 + c;
  float m = M[c];
  float r[8];
  #pragma unroll
  for (int j = 0; j < 8; j++) {
    float d = __fsub_rn(bf2f(pl[(size_t)j * 256]), m);
    r[j] = __fmul_rn(d, d);
  }
  for (int b = 1; b < nb; b++) {
    #pragma unroll
    for (int j = 0; j < 8; j++) {
      float d = __fsub_rn(bf2f(pl[(size_t)(8 * b + j) * 256]), m);
      r[j] = __fadd_rn(r[j], __fmul_rn(d, d));
    }
  }
  float lv = __fadd_rn(
      __fadd_rn(__fadd_rn(r[0], r[1]), __fadd_rn(r[2], r[3])),
      __fadd_rn(__fadd_rn(r[4], r[5]), __fadd_rn(r[6], r[7])));
  PVL[(size_t)blockIdx.x * 256 + c] = lv;
}

// varT combine: exact tree over 32 leaves, seq over n, /100352, CR rsqrt
__global__ __launch_bounds__(256) void k_vcmbT(const float* __restrict__ PVL,
    float* __restrict__ R)
{
  int c = threadIdx.x;
  float acc = 0.f;
  for (int n = 0; n < 32; n++) {
    float ch[8];
    #pragma unroll
    for (int q = 0; q < 8; q++) {
      const float* p = PVL + ((size_t)(n * 32 + q * 4)) * 256 + c;
      ch[q] = __fadd_rn(__fadd_rn(p[0], p[256]), __fadd_rn(p[512], p[768]));
    }
    float s0 = __fadd_rn(ch[0], ch[1]), s1 = __fadd_rn(ch[2], ch[3]);
    float s2 = __fadd_rn(ch[4], ch[5]), s3 = __fadd_rn(ch[6], ch[7]);
    float plane = __fadd_rn(__fadd_rn(s0, s1), __fadd_rn(s2, s3));
    acc = __fadd_rn(acc, plane);
  }
  float v = __fdiv_rn(acc, 100352.0f);
  R[c] = (float)(1.0 / sqrt((double)__fadd_rn(v, 1e-5f)));
}

// ---------------------------------------------------------------------------
// K2: apply1: SB = sign( ((t1-m)*r)*g + b + x ). 4 px/thread, vectorized
// f32x4 x-loads + uint c1-loads; XOR block-swizzled LDS staging.
// ---------------------------------------------------------------------------
__global__ __launch_bounds__(256) void k_apply1(const float* __restrict__ x,
    const signed char* __restrict__ c1, const float* __restrict__ a1,
    const float* __restrict__ M1, const float* __restrict__ R1,
    const float* __restrict__ g1, const float* __restrict__ b1,
    unsigned short* __restrict__ s1)
{
  __shared__ __align__(16) unsigned short lb[32 * 264];
  int bid = blockIdx.x;
  int n = bid / 98, pb = bid % 98;
  int px0 = pb * 32;
  int t = threadIdx.x;

  int pxg = (t & 7) * 4, cb = t >> 3;
  #pragma unroll
  for (int j = 0; j < 8; j++) {
    int c = cb + j * 32;
    size_t gidx = ((size_t)(n * 256 + c)) * HWSZ + px0 + pxg;
    f32x4 xv = *(const f32x4*)(x + gidx);
    unsigned int cp = *(const unsigned int*)(const void*)(c1 + gidx);
    float av = a1[c];
    float m1 = M1[c], r1 = R1[c], gg1 = g1[c], bb1 = b1[c];
    #pragma unroll
    for (int e = 0; e < 4; e++) {
      int row = pxg + e;
      int idx = row * 264 + (c ^ (((row >> 2) & 7) << 3));
      float v = (float)(int)(signed char)(unsigned char)(cp >> (8 * e));
      float t1 = (v >= 0.f) ? v : __fmul_rn(av, v);
      float xn = __fmul_rn(__fsub_rn(t1, m1), r1);
      float bn = __fadd_rn(__fmul_rn(xn, gg1), bb1);
      float o1 = __fadd_rn(bn, xv[e]);
      lb[idx] = sgnf_bf16(o1);
    }
  }
  __syncthreads();
  unsigned short* sp = s1 + ((size_t)(n * HWSZ + px0)) * 256;
  for (int j = 0; j < 4; j++) {
    int f = j * 256 + t;
    int px = f >> 5, c16 = f & 31;
    int cs = (c16 ^ ((px >> 2) & 7)) * 8;
    *(u16x8*)(sp + px * 256 + c16 * 8) = *(const u16x8*)(lb + px * 264 + cs);
  }
}

// ---------------------------------------------------------------------------
// K4: apply2: SB = sign( bn2(t2) + (bn1(t1)+x) ). In-place swizzled LDS,
// 4 px/thread vectorized x/c1 loads. Slot (px,c) read+written by same thread.
// ---------------------------------------------------------------------------
__global__ __launch_bounds__(256) void k_apply2(const float* __restrict__ x,
    const signed char* __restrict__ c1, const unsigned short* __restrict__ t2,
    const float* __restrict__ a1,
    const float* __restrict__ M1, const float* __restrict__ R1,
    const float* __restrict__ g1, const float* __restrict__ b1,
    const float* __restrict__ M2, const float* __restrict__ R2,
    const float* __restrict__ g2, const float* __restrict__ b2,
    unsigned short* __restrict__ s2)
{
  __shared__ __align__(16) unsigned short lb[32 * 264];
  int bid = blockIdx.x;
  int n = bid / 98, pb = bid % 98;
  int px0 = pb * 32;
  int t = threadIdx.x;

  const unsigned short* tp = t2 + ((size_t)(n * HWSZ + px0)) * 256;
  for (int j = 0; j < 4; j++) {
    int f = j * 256 + t;
    int px = f >> 5, c16 = f & 31;
    int cs = (c16 ^ ((px >> 2) & 7)) * 8;
    *(u16x8*)(lb + px * 264 + cs) = *(const u16x8*)(tp + px * 256 + c16 * 8);
  }
  __syncthreads();

  int pxg = (t & 7) * 4, cb = t >> 3;
  #pragma unroll
  for (int j = 0; j < 8; j++) {
    int c = cb + j * 32;
    size_t gidx = ((size_t)(n * 256 + c)) * HWSZ + px0 + pxg;
    f32x4 xv = *(const f32x4*)(x + gidx);
    unsigned int cp = *(const unsigned int*)(const void*)(c1 + gidx);
    float av = a1[c];
    float m1 = M1[c], r1 = R1[c], gg1 = g1[c], bb1 = b1[c];
    float m2 = M2[c], r2 = R2[c], gg2 = g2[c], bb2 = b2[c];
    #pragma unroll
    for (int e = 0; e < 4; e++) {
      int row = pxg + e;
      int idx = row * 264 + (c ^ (((row >> 2) & 7) << 3));
      float v = (float)(int)(signed char)(unsigned char)(cp >> (8 * e));
      float t1 = (v >= 0.f) ? v : __fmul_rn(av, v);
      float xn1 = __fmul_rn(__fsub_rn(t1, m1), r1);
      float bn1v = __fadd_rn(__fmul_rn(xn1, gg1), bb1);
      float o1 = __fadd_rn(bn1v, xv[e]);
      float t2v = bf2f(lb[idx]);
      float xn2 = __fmul_rn(__fsub_rn(t2v, m2), r2);
      float bn2v = __fadd_rn(__fmul_rn(xn2, gg2), bb2);
      float o2 = __fadd_rn(bn2v, o1);
      lb[idx] = sgnf_bf16(o2);
    }
  }
  __syncthreads();
  unsigned short* sp = s2 + ((size_t)(n * HWSZ + px0)) * 256;
  for (int j = 0; j < 4; j++) {
    int f = j * 256 + t;
    int px = f >> 5, c16 = f & 31;
    int cs = (c16 ^ ((px >> 2) & 7)) * 8;
    *(u16x8*)(sp + px * 256 + c16 * 8) = *(const u16x8*)(lb + px * 264 + cs);
  }
}

// ---------------------------------------------------------------------------
// K6: apply3: SB = sign( bn3(t3) ), f32-replica, elementwise NHWC
// ---------------------------------------------------------------------------
__global__ __launch_bounds__(256) void k_apply3(const unsigned short* __restrict__ t3,
    const float* __restrict__ M3, const float* __restrict__ R3,
    const float* __restrict__ g3, const float* __restrict__ b3,
    unsigned short* __restrict__ s3)
{
  size_t idx = ((size_t)blockIdx.x * 256 + threadIdx.x) * 8;
  int c0 = (int)(idx & 255);
  u16x8 v = *(const u16x8*)(t3 + idx);
  u16x8 o;
  #pragma unroll
  for (int e = 0; e < 8; e++) {
    int c = c0 + e;
    float t = bf2f(v[e]);
    float xn = __fmul_rn(__fsub_rn(t, M3[c]), R3[c]);
    float bn = __fadd_rn(__fmul_rn(xn, g3[c]), b3[c]);
    o[e] = sgnf_bf16(bn);
  }
  *(u16x8*)(s3 + idx) = o;
}

// ---------------------------------------------------------------------------
// K8: final: out = bn4(t4), NHWC bf16 -> NCHW fp32. 16-px tile, [px][260]
// ---------------------------------------------------------------------------
__global__ __launch_bounds__(256) void k_final(const unsigned short* __restrict__ t4,
    const float* __restrict__ M4, const float* __restrict__ R4,
    const float* __restrict__ g4, const float* __restrict__ b4,
    float* __restrict__ outp)
{
  __shared__ __align__(16) float lt[16 * 260];
  int bid = blockIdx.x;
  int n = bid / 196, pb = bid % 196;
  int px0 = pb * 16;
  int t = threadIdx.x;

  const unsigned short* tp = t4 + ((size_t)(n * HWSZ + px0)) * 256;
  for (int j = 0; j < 2; j++) {
    int f = j * 256 + t;
    int px = f >> 5, c16 = f & 31;
    u16x8 v = *(const u16x8*)(tp + px * 256 + c16 * 8);
    f32x4 o0, o1;
    #pragma unroll
    for (int e = 0; e < 4; e++) {
      int c = c16 * 8 + e;
      float tv = bf2f(v[e]);
      float xn = __fmul_rn(__fsub_rn(tv, M4[c]), R4[c]);
      o0[e] = __fadd_rn(__fmul_rn(xn, g4[c]), b4[c]);
    }
    #pragma unroll
    for (int e = 0; e < 4; e++) {
      int c = c16 * 8 + 4 + e;
      float tv = bf2f(v[4 + e]);
      float xn = __fmul_rn(__fsub_rn(tv, M4[c]), R4[c]);
      o1[e] = __fadd_rn(__fmul_rn(xn, g4[c]), b4[c]);
    }
    *(f32x4*)(lt + px * 260 + c16 * 8) = o0;
    *(f32x4*)(lt + px * 260 + c16 * 8 + 4) = o1;
  }
  __syncthreads();
  for (int j = 0; j < 4; j++) {
    int f = j * 256 + t;
    int c = f >> 2, q = f & 3;
    f32x4 v;
    #pragma unroll
    for (int e = 0; e < 4; e++) v[e] = lt[(q * 4 + e) * 260 + c];
    *(f32x4*)(outp + ((size_t)(n * 256 + c)) * HWSZ + px0 + q * 4) = v;
  }
}

// ---------------------------------------------------------------------------
// K3/5/7: GEMM: TB = prelu(SB x BS^T), exact ints via bf16 MFMA, padded LDS,
// + fused per-block column mean-partials (exact int f32 sums, order-free)
// ---------------------------------------------------------------------------
__global__ __launch_bounds__(512) void k_gemm(
    const unsigned short* __restrict__ sIn, const unsigned short* __restrict__ bsg,
    const float* __restrict__ aP, unsigned short* __restrict__ tOut,
    float* __restrict__ PM)
{
  __shared__ __align__(16) unsigned short As[128 * 72];
  __shared__ __align__(16) unsigned short Bs[256 * 72];
  __shared__ float red[8][4][16];
  const int t = threadIdx.x;
  const int lane = t & 63;
  const int wid = t >> 6;
  const int wm = wid >> 2, wn = wid & 3;
  const int lr = lane & 15, lk = lane >> 4;
  const int pix0 = blockIdx.x * 128;
  const unsigned short* Ap = sIn + (size_t)pix0 * 256;

  f32x4 acc[4][4];
  #pragma unroll
  for (int i = 0; i < 4; i++)
    #pragma unroll
    for (int j = 0; j < 4; j++)
      acc[i][j] = (f32x4){0.f, 0.f, 0.f, 0.f};

  for (int kt = 0; kt < 4; kt++) {
    const int k0 = kt * 64;
    if (kt) __syncthreads();
    #pragma unroll
    for (int j = 0; j < 2; j++) {
      int idx = j * 512 + t;
      int row = idx >> 3, kc = idx & 7;
      u16x8 v = *(const u16x8*)(Ap + (size_t)row * 256 + k0 + kc * 8);
      *(u16x8*)(As + row * 72 + kc * 8) = v;
    }
    #pragma unroll
    for (int j = 0; j < 4; j++) {
      int idx = j * 512 + t;
      int row = idx >> 3, kc = idx & 7;
      u16x8 v = *(const u16x8*)(bsg + (size_t)row * 256 + k0 + kc * 8);
      *(u16x8*)(Bs + row * 72 + kc * 8) = v;
    }
    __syncthreads();
    #pragma unroll
    for (int h = 0; h < 2; h++) {
      bf16x8 af[4], bfr[4];
      #pragma unroll
      for (int mf = 0; mf < 4; mf++)
        af[mf] = *(const bf16x8*)(As + (wm * 64 + mf * 16 + lr) * 72 + (h * 4 + lk) * 8);
      #pragma unroll
      for (int nf = 0; nf < 4; nf++)
        bfr[nf] = *(const bf16x8*)(Bs + (wn * 64 + nf * 16 + lr) * 72 + (h * 4 + lk) * 8);
      #pragma unroll
      for (int mf = 0; mf < 4; mf++)
        #pragma unroll
        for (int nf = 0; nf < 4; nf++)
          acc[mf][nf] = __builtin_amdgcn_mfma_f32_16x16x32_bf16(
              af[mf], bfr[nf], acc[mf][nf], 0, 0, 0);
    }
  }

  float csum[4];
  #pragma unroll
  for (int nf = 0; nf < 4; nf++) csum[nf] = 0.f;

  #pragma unroll
  for (int nf = 0; nf < 4; nf++) {
    int gcol = wn * 64 + nf * 16 + lr;
    float av = aP[gcol];
    #pragma unroll
    for (int mf = 0; mf < 4; mf++) {
      #pragma unroll
      for (int r = 0; r < 4; r++) {
        int grow = pix0 + wm * 64 + mf * 16 + lk * 4 + r;
        float u = acc[mf][nf][r];
        float tv = (u >= 0.f) ? u : __fmul_rn(av, u);   // exact quarter-ints
        tOut[(size_t)grow * 256 + gcol] = f2bf(tv);
        csum[nf] = __fadd_rn(csum[nf], tv);             // exact, order-free
      }
    }
  }
  #pragma unroll
  for (int nf = 0; nf < 4; nf++) {
    csum[nf] = __fadd_rn(csum[nf], __shfl_xor(csum[nf], 16));
    csum[nf] = __fadd_rn(csum[nf], __shfl_xor(csum[nf], 32));
  }
  if (lane < 16) {
    #pragma unroll
    for (int nf = 0; nf < 4; nf++) red[wid][nf][lane] = csum[nf];
  }
  __syncthreads();
  if (t < 256) {
    int wn2 = t >> 6, nf2 = (t >> 4) & 3, lr2 = t & 15;
    PM[(size_t)blockIdx.x * 256 + t] =
        __fadd_rn(red[wn2][nf2][lr2], red[wn2 + 4][nf2][lr2]);
  }
}

// ---------------------------------------------------------------------------
extern "C" void kernel_launch(void* const* d_in, const int* in_sizes, int n_in,
                              void* d_out, int out_size, void* d_ws, size_t ws_size,
                              hipStream_t stream)
{
  const float* x   = (const float*)d_in[0];
  const float* wdw = (const float*)d_in[1];
  const float* w1  = (const float*)d_in[2];
  const float* w2  = (const float*)d_in[3];
  const float* w3  = (const float*)d_in[4];
  const float* a1  = (const float*)d_in[5];
  const float* a2  = (const float*)d_in[6];
  const float* a3  = (const float*)d_in[7];
  const float* a4  = (const float*)d_in[8];
  const float* g1  = (const float*)d_in[9];
  const float* b1  = (const float*)d_in[10];
  const float* g2  = (const float*)d_in[11];
  const float* b2  = (const float*)d_in[12];
  const float* g3  = (const float*)d_in[13];
  const float* b3  = (const float*)d_in[14];
  const float* g4  = (const float*)d_in[15];
  const float* b4  = (const float*)d_in[16];

  char* ws = (char*)d_ws;
  unsigned short* SB  = (unsigned short*)ws;                  // 51,380,224 B
  unsigned short* TB  = (unsigned short*)(ws + 51380224);     // 51,380,224 B
  signed char*    c1  = (signed char*)(ws + 102760448);       // 25,690,112 B
  unsigned short* BS  = (unsigned short*)(ws + 128450560);    //    393,216 B
  float*          BIG = (float*)(ws + 128843776);             //  1,048,576 B (PM / P1 / PVL)
  float*          PV  = (float*)(ws + 129892352);             //     32,768 B
  float*          MR  = (float*)(ws + 129925120);             //      8,192 B
  float*          outp = (float*)d_out;                       // fp32 NCHW

  float* P1  = BIG;   // [32][256] plane sums (layer1)
  float* PM  = BIG;   // [784][256] gemm block sums
  float* PVL = BIG;   // [1024][256] varT leaf sums
  float* M1 = MR;        float* R1 = MR + 256;
  float* M2 = MR + 512;  float* R2 = MR + 768;
  float* M3 = MR + 1024; float* R3 = MR + 1280;
  float* M4 = MR + 1536; float* R4 = MR + 1792;

  k_prepw <<<dim3(768),  dim3(256), 0, stream>>>(w1, w2, w3, BS);
  k_dwconv<<<dim3(8192), dim3(256), 0, stream>>>(x, wdw, a1, c1, P1);

  // BN1: fused mean partials, parallel np-ordered var, CR rsqrt
  k_cmb   <<<dim3(1),    dim3(256), 0, stream>>>(P1, M1);
  k_var1  <<<dim3(8192), dim3(256), 0, stream>>>(c1, a1, M1, PV);
  k_vcmb  <<<dim3(1),    dim3(256), 0, stream>>>(PV, R1);
  k_apply1<<<dim3(3136), dim3(256), 0, stream>>>(x, c1, a1, M1, R1, g1, b1, SB);

  // layer 2
  k_gemm  <<<dim3(784),  dim3(512), 0, stream>>>(SB, BS, a2, TB, PM);
  k_cmbG  <<<dim3(1),    dim3(256), 0, stream>>>(PM, M2);
  k_varT  <<<dim3(1024), dim3(256), 0, stream>>>(TB, M2, PVL);
  k_vcmbT <<<dim3(1),    dim3(256), 0, stream>>>(PVL, R2);
  k_apply2<<<dim3(3136), dim3(256), 0, stream>>>(x, c1, TB, a1,
                                                 M1, R1, g1, b1, M2, R2, g2, b2, SB);

  // layer 3
  k_gemm  <<<dim3(784),  dim3(512), 0, stream>>>(SB, BS + 65536, a3, TB, PM);
  k_cmbG  <<<dim3(1),    dim3(256), 0, stream>>>(PM, M3);
  k_varT  <<<dim3(1024), dim3(256), 0, stream>>>(TB, M3, PVL);
  k_vcmbT <<<dim3(1),    dim3(256), 0, stream>>>(PVL, R3);
  k_apply3<<<dim3(12544),dim3(256), 0, stream>>>(TB, M3, R3, g3, b3, SB);

  // layer 4
  k_gemm  <<<dim3(784),  dim3(512), 0, stream>>>(SB, BS + 131072, a4, TB, PM);
  k_cmbG  <<<dim3(1),    dim3(256), 0, stream>>>(PM, M4);
  k_varT  <<<dim3(1024), dim3(256), 0, stream>>>(TB, M4, PVL);
  k_vcmbT <<<dim3(1),    dim3(256), 0, stream>>>(PVL, R4);
  k_final <<<dim3(6272), dim3(256), 0, stream>>>(TB, M4, R4, g4, b4, outp);
}